// Round 11
// baseline (465.887 us; speedup 1.0000x reference)
//
#include <hip/hip_runtime.h>

#define BB 8
#define TT 4
#define CIN 512
#define CAF 64
#define HH 11
#define WW 20
#define PP 220           // H*W positions
#define PPAD 256
#define AREAL 2784
#define AP 2816          // padded anchors
#define DD 704           // C_AF*H
#define NH 80            // padded head cols (2 cls + 74 reg)
#define NHP 128          // padded head rows for B-staging
#define KH 3520          // 5*DD
#define NATT 2783        // A-1

typedef __attribute__((ext_vector_type(8))) short bf16x8;
typedef __attribute__((ext_vector_type(4))) float floatx4;

__device__ __forceinline__ short f2bf(float f) {
  unsigned u = __float_as_uint(f);
  u += 0x7fffu + ((u >> 16) & 1u);
  return (short)(u >> 16);
}
__device__ __forceinline__ float bf2f(short s) {
  return __uint_as_float(((unsigned)(unsigned short)s) << 16);
}

__device__ __forceinline__ void gload_lds16(const void* g, void* l) {
  __builtin_amdgcn_global_load_lds(
      (const __attribute__((address_space(1))) void*)g,
      (__attribute__((address_space(3))) void*)l, 16, 0, 0);
}

// ---------------- xT[bt][p(256)][c(512)] = bf16(x[bt][c][p]), p>=220 -> 0
__global__ __launch_bounds__(256)
void transpose_x_kernel(const float* __restrict__ x, short* __restrict__ xT)
{
  int bt = blockIdx.x;        // 0..31
  int c0 = blockIdx.y * 32;   // 0..480
  __shared__ float xs[32 * PP];
  int tid = threadIdx.x;
  const float* xp = x + ((long)bt * CIN + c0) * PP;
  for (int i = tid; i < 32 * PP; i += 256) xs[i] = xp[i];
  __syncthreads();
  short* op = xT + (long)bt * PPAD * CIN + c0;
  for (int j = tid; j < PPAD * 32; j += 256) {
    int p = j >> 5, cc = j & 31;
    short v = 0;
    if (p < PP) v = f2bf(xs[cc * PP + p]);
    op[(long)p * CIN + cc] = v;
  }
}

// ---------------- w_bf16[n(128)][c(512)]: n<64 -> conv1_w[n][c], else 0
__global__ void prep_wbf_kernel(const float* __restrict__ w, short* __restrict__ wb)
{
  int idx = blockIdx.x * 256 + threadIdx.x;
  if (idx >= 128 * CIN) return;
  int n = idx >> 9, c = idx & 511;
  wb[idx] = (n < CAF) ? f2bf(w[(long)n * CIN + c]) : (short)0;
}

// ---------------- gidx[a][hh] = invalid ? -1 : (hh*20+xw)*128
__global__ void prep_gidx_kernel(const int* __restrict__ cut_xs, const int* __restrict__ invalid,
                                 int* __restrict__ gidx)
{
  int idx = blockIdx.x * 256 + threadIdx.x;
  if (idx >= AREAL * HH) return;
  int hh = idx % HH;
  gidx[idx] = invalid[idx] ? -1 : (hh * WW + cut_xs[idx]) * 128;
}

// ---------------- gather cur (t=3), d-major vectorized
__global__ __launch_bounds__(256)
void gather_cur_kernel(const short* __restrict__ fpo_base, const int* __restrict__ gidx,
                       short* __restrict__ curR)
{
  int g = blockIdx.y;
  int idx = blockIdx.x * 256 + threadIdx.x;   // over AP*88
  int a = idx / 88;
  int ch = idx - a * 88;
  int d0 = ch * 8;
  bf16x8 v = {};
  if (a < AREAL) {
    const short* fp = fpo_base + ((long)g * TT + 3) * PPAD * 128;
    #pragma unroll
    for (int e = 0; e < 8; ++e) {
      int d = d0 + e;
      int o = d / 11;
      int hh = d - o * 11;
      int gi = gidx[a * 11 + hh];
      v[e] = (gi < 0) ? (short)0 : fp[gi + o];
    }
  }
  *(bf16x8*)(curR + ((long)g * AP + a) * DD + d0) = v;
}

// ---------------- attw_T[n][d] = att_w[d][n] bf16 (pad -> 0)
__global__ __launch_bounds__(256)
void prep_attw_kernel(const float* __restrict__ att_w, short* __restrict__ attwT)
{
  int n0 = blockIdx.x * 32;
  int d0 = blockIdx.y * 32;
  __shared__ float tile[32][33];
  int tid = threadIdx.x;
  for (int i = tid; i < 1024; i += 256) {
    int r = i >> 5, c = i & 31;
    int d = d0 + r, n = n0 + c;
    tile[r][c] = (d < DD && n < NATT) ? att_w[(long)d * NATT + n] : 0.f;
  }
  __syncthreads();
  for (int i = tid; i < 1024; i += 256) {
    int r = i >> 5, c = i & 31;
    attwT[(long)(n0 + r) * DD + d0 + c] = f2bf(tile[c][r]);
  }
}

// ---------------- headwT[n(128)][k]: n<2 cls_w[k][n]; 2<=n<76 reg_w[k][n-2]; else 0
__global__ void prep_headw_kernel(const float* __restrict__ cls_w, const float* __restrict__ reg_w,
                                  short* __restrict__ headwT)
{
  long idx = (long)blockIdx.x * 256 + threadIdx.x;
  if (idx >= (long)NHP * KH) return;
  int n = (int)(idx / KH), k = (int)(idx % KH);
  float v = 0.f;
  if (n < 2) v = cls_w[(long)k * 2 + n];
  else if (n < 76) v = reg_w[(long)k * 74 + (n - 2)];
  headwT[idx] = f2bf(v);
}

// ================= 256x256 deep-pipelined NT GEMM (round-8 schedule) =================
__global__ __launch_bounds__(512, 2)
void gemm256_nt_kernel(const short* __restrict__ A, long long aBatch, int lda,
                       const short* __restrict__ Bt, long long bBatch, int ldb,
                       short* __restrict__ C, long long cBatch, int ldc,
                       int K, const float* __restrict__ bias, int biasN)
{
  int gx = gridDim.x, gy = gridDim.y;
  int nwg = gx * gy * gridDim.z;
  int o = blockIdx.x + gx * (blockIdx.y + gy * blockIdx.z);
  int xcd = o & 7, pos = o >> 3;
  int q = nwg >> 3, r = nwg & 7;
  int nid = (xcd < r ? xcd * (q + 1) : r * (q + 1) + (xcd - r) * q) + pos;
  int bx = nid % gx; int tq = nid / gx; int by = tq % gy; int bz = tq / gy;

  A  += (long long)bz * aBatch;
  Bt += (long long)bz * bBatch;
  C  += (long long)bz * cBatch;
  int M0 = by * 256, N0 = bx * 256;

  __shared__ short lds_a[2 * 256 * 64];
  __shared__ short lds_b[2 * 256 * 64];

  int tid = threadIdx.x, lane = tid & 63, w = tid >> 6;
  int wr = w >> 2, wc = w & 3;

  floatx4 acc[8][4];
  #pragma unroll
  for (int m = 0; m < 8; ++m)
    #pragma unroll
    for (int n = 0; n < 4; ++n) acc[m][n] = floatx4{0.f, 0.f, 0.f, 0.f};

  int rl = tid >> 3, sl = tid & 7;
  int ssl = sl ^ (rl & 7);
  const short* aS = A  + (long)(M0 + rl) * lda + ssl * 8;
  const short* bS = Bt + (long)(N0 + rl) * ldb + ssl * 8;
  char* la0 = (char*)lds_a;
  char* lb0 = (char*)lds_b;
  int wub = (tid & ~63) * 16;

  auto stage = [&](int kt, int buf) {
    long ko = (long)kt * 64;
    #pragma unroll
    for (int c = 0; c < 4; ++c) {
      gload_lds16(aS + (long)c * 64 * lda + ko, la0 + buf * 32768 + c * 8192 + wub);
      gload_lds16(bS + (long)c * 64 * ldb + ko, lb0 + buf * 32768 + c * 8192 + wub);
    }
  };
  auto rdA = [&](int buf, int mf, int kk) -> bf16x8 {
    int row = wr * 128 + mf * 16 + (lane & 15);
    int phys = (kk * 4 + (lane >> 4)) ^ (lane & 7);
    return *(const bf16x8*)(la0 + buf * 32768 + row * 128 + phys * 16);
  };
  auto rdB = [&](int buf, int nf, int kk) -> bf16x8 {
    int row = wc * 64 + nf * 16 + (lane & 15);
    int phys = (kk * 4 + (lane >> 4)) ^ (lane & 7);
    return *(const bf16x8*)(lb0 + buf * 32768 + row * 128 + phys * 16);
  };

  int nt = K >> 6;
  stage(0, 0);
  stage(1, 1);
  asm volatile("s_waitcnt vmcnt(8)" ::: "memory");
  __builtin_amdgcn_sched_barrier(0);
  __builtin_amdgcn_s_barrier();
  __builtin_amdgcn_sched_barrier(0);

  for (int t = 0; t < nt; ++t) {
    int buf = t & 1;
    bf16x8 A0[2][4], A1[2][4], B0[2][2], B1[2][2];
    #pragma unroll
    for (int kk = 0; kk < 2; ++kk) {
      #pragma unroll
      for (int i = 0; i < 4; ++i) A0[kk][i] = rdA(buf, i, kk);
      #pragma unroll
      for (int j = 0; j < 2; ++j) B0[kk][j] = rdB(buf, j, kk);
    }
    __builtin_amdgcn_s_setprio(1);
    #pragma unroll
    for (int kk = 0; kk < 2; ++kk)
      #pragma unroll
      for (int i = 0; i < 4; ++i)
        #pragma unroll
        for (int j = 0; j < 2; ++j)
          acc[i][j] = __builtin_amdgcn_mfma_f32_16x16x32_bf16(A0[kk][i], B0[kk][j], acc[i][j], 0, 0, 0);
    __builtin_amdgcn_s_setprio(0);
    #pragma unroll
    for (int kk = 0; kk < 2; ++kk)
      #pragma unroll
      for (int j = 0; j < 2; ++j) B1[kk][j] = rdB(buf, 2 + j, kk);
    __builtin_amdgcn_s_setprio(1);
    #pragma unroll
    for (int kk = 0; kk < 2; ++kk)
      #pragma unroll
      for (int i = 0; i < 4; ++i)
        #pragma unroll
        for (int j = 0; j < 2; ++j)
          acc[i][2 + j] = __builtin_amdgcn_mfma_f32_16x16x32_bf16(A0[kk][i], B1[kk][j], acc[i][2 + j], 0, 0, 0);
    __builtin_amdgcn_s_setprio(0);
    #pragma unroll
    for (int kk = 0; kk < 2; ++kk)
      #pragma unroll
      for (int i = 0; i < 4; ++i) A1[kk][i] = rdA(buf, 4 + i, kk);
    __builtin_amdgcn_s_setprio(1);
    #pragma unroll
    for (int kk = 0; kk < 2; ++kk)
      #pragma unroll
      for (int i = 0; i < 4; ++i)
        #pragma unroll
        for (int j = 0; j < 2; ++j)
          acc[4 + i][2 + j] = __builtin_amdgcn_mfma_f32_16x16x32_bf16(A1[kk][i], B1[kk][j], acc[4 + i][2 + j], 0, 0, 0);
    __builtin_amdgcn_s_setprio(0);
    __builtin_amdgcn_sched_barrier(0);
    __builtin_amdgcn_s_barrier();
    __builtin_amdgcn_sched_barrier(0);
    if (t + 2 < nt) stage(t + 2, buf);
    __builtin_amdgcn_s_setprio(1);
    #pragma unroll
    for (int kk = 0; kk < 2; ++kk)
      #pragma unroll
      for (int i = 0; i < 4; ++i)
        #pragma unroll
        for (int j = 0; j < 2; ++j)
          acc[4 + i][j] = __builtin_amdgcn_mfma_f32_16x16x32_bf16(A1[kk][i], B0[kk][j], acc[4 + i][j], 0, 0, 0);
    __builtin_amdgcn_s_setprio(0);
    if (t + 2 < nt) {
      asm volatile("s_waitcnt vmcnt(8)" ::: "memory");
    } else {
      asm volatile("s_waitcnt vmcnt(0)" ::: "memory");
    }
    __builtin_amdgcn_sched_barrier(0);
    __builtin_amdgcn_s_barrier();
    __builtin_amdgcn_sched_barrier(0);
  }

  #pragma unroll
  for (int mf = 0; mf < 8; ++mf) {
    #pragma unroll
    for (int nf = 0; nf < 4; ++nf) {
      int col = N0 + wc * 64 + nf * 16 + (lane & 15);
      float bv = 0.f;
      if (bias) bv = (col < biasN) ? bias[col] : 0.f;
      #pragma unroll
      for (int rr = 0; rr < 4; ++rr) {
        int rowc = M0 + wr * 128 + mf * 16 + (lane >> 4) * 4 + rr;
        C[(long)rowc * ldc + col] = f2bf(acc[mf][nf][rr] + bv);
      }
    }
  }
}

// ---------------- batched NT GEMM: 128x128 tile, 2-phase dbuf (conv + curW3T)
template<int WITH_BIAS>
__global__ __launch_bounds__(256)
void gemm_nt_kernel(const short* __restrict__ A, long long aBatch, int lda,
                    const short* __restrict__ Bt, long long bBatch, int ldb,
                    short* __restrict__ C, long long cBatch, int ldc,
                    int K, const float* __restrict__ bias, int biasN)
{
  int gx = gridDim.x, gy = gridDim.y;
  int nwg = gx * gy * gridDim.z;
  int o = blockIdx.x + gx * (blockIdx.y + gy * blockIdx.z);
  int xcd = o & 7, pos = o >> 3;
  int q = nwg >> 3, r = nwg & 7;
  int nid = (xcd < r ? xcd * (q + 1) : r * (q + 1) + (xcd - r) * q) + pos;
  int bx = nid % gx; int t = nid / gx; int by = t % gy; int bz = t / gy;

  A  += (long long)bz * aBatch;
  Bt += (long long)bz * bBatch;
  C  += (long long)bz * cBatch;
  int m0 = by * 128;
  int n0 = bx * 128;

  __shared__ short lds_a[2 * 128 * 32];
  __shared__ short lds_b[2 * 128 * 32];

  int tid = threadIdx.x;
  int lane = tid & 63;
  int wid = tid >> 6;
  int wr = wid >> 1, wc = wid & 1;
  int row = tid >> 2;
  int slot = tid & 3;

  floatx4 acc[4][4];
  #pragma unroll
  for (int m = 0; m < 4; ++m)
    #pragma unroll
    for (int n = 0; n < 4; ++n) acc[m][n] = floatx4{0.f, 0.f, 0.f, 0.f};

  int wbase = (tid & ~63) * 16;
  int ks0 = slot ^ ((row >> 1) & 3);
  int ks1 = slot ^ (((row + 64) >> 1) & 3);
  const short* ar0 = A  + (long)(m0 + row) * lda + ks0 * 8;
  const short* ar1 = A  + (long)(m0 + row + 64) * lda + ks1 * 8;
  const short* br0 = Bt + (long)(n0 + row) * ldb + ks0 * 8;
  const short* br1 = Bt + (long)(n0 + row + 64) * ldb + ks1 * 8;

  auto stage = [&](int kt, int buf) {
    int k0 = kt * 32;
    char* la = (char*)lds_a + buf * 8192 + wbase;
    char* lb = (char*)lds_b + buf * 8192 + wbase;
    gload_lds16(ar0 + k0, la);
    gload_lds16(ar1 + k0, la + 4096);
    gload_lds16(br0 + k0, lb);
    gload_lds16(br1 + k0, lb + 4096);
  };

  int nk = K >> 5;
  stage(0, 0);
  __syncthreads();
  int cur = 0;
  for (int kt = 0; kt < nk; ++kt) {
    if (kt + 1 < nk) stage(kt + 1, cur ^ 1);
    const char* ba = (const char*)lds_a + cur * 8192;
    const char* bb = (const char*)lds_b + cur * 8192;
    bf16x8 af[4], bfv[4];
    #pragma unroll
    for (int m = 0; m < 4; ++m) {
      int rw = wr * 64 + m * 16 + (lane & 15);
      int pp = (lane >> 4) ^ ((rw >> 1) & 3);
      af[m] = *(const bf16x8*)(ba + rw * 64 + (pp << 4));
    }
    #pragma unroll
    for (int n = 0; n < 4; ++n) {
      int rw = wc * 64 + n * 16 + (lane & 15);
      int pp = (lane >> 4) ^ ((rw >> 1) & 3);
      bfv[n] = *(const bf16x8*)(bb + rw * 64 + (pp << 4));
    }
    #pragma unroll
    for (int m = 0; m < 4; ++m)
      #pragma unroll
      for (int n = 0; n < 4; ++n)
        acc[m][n] = __builtin_amdgcn_mfma_f32_16x16x32_bf16(af[m], bfv[n], acc[m][n], 0, 0, 0);
    __syncthreads();
    cur ^= 1;
  }

  #pragma unroll
  for (int m = 0; m < 4; ++m) {
    #pragma unroll
    for (int n = 0; n < 4; ++n) {
      int col = n0 + wc * 64 + n * 16 + (lane & 15);
      float bv = 0.f;
      if (WITH_BIAS) bv = (col < biasN) ? bias[col] : 0.f;
      #pragma unroll
      for (int rr = 0; rr < 4; ++rr) {
        int rowc = m0 + wr * 64 + m * 16 + (lane >> 4) * 4 + rr;
        C[(long)rowc * ldc + col] = f2bf(acc[m][n][rr] + bv);
      }
    }
  }
}

// ---------------- per-row softmax + shifted M-row write in place (vectorized)
__global__ __launch_bounds__(256)
void softmax_shift_kernel(short* __restrict__ scores)
{
  int g = blockIdx.y;
  int i = blockIdx.x;   // 0..2783
  short* row = scores + (long)g * AP * AP + (long)i * AP;
  __shared__ float vals[NATT];
  __shared__ float red[4];
  int tid = threadIdx.x;

  float lmax = -1e30f;
  for (int jc = tid; jc < 348; jc += 256) {
    bf16x8 v8 = *(const bf16x8*)(row + jc * 8);
    #pragma unroll
    for (int e = 0; e < 8; ++e) {
      int j = jc * 8 + e;
      float f = bf2f(v8[e]);
      if (j < NATT) { vals[j] = f; lmax = fmaxf(lmax, f); }
    }
  }
  #pragma unroll
  for (int off = 32; off; off >>= 1) lmax = fmaxf(lmax, __shfl_down(lmax, off, 64));
  if ((tid & 63) == 0) red[tid >> 6] = lmax;
  __syncthreads();
  float mx = fmaxf(fmaxf(red[0], red[1]), fmaxf(red[2], red[3]));
  __syncthreads();

  float lsum = 0.f;
  for (int j = tid; j < NATT; j += 256) {
    float e = __expf(vals[j] - mx);
    vals[j] = e;
    lsum += e;
  }
  #pragma unroll
  for (int off = 32; off; off >>= 1) lsum += __shfl_down(lsum, off, 64);
  if ((tid & 63) == 0) red[tid >> 6] = lsum;
  __syncthreads();
  float inv = 1.f / (red[0] + red[1] + red[2] + red[3]);
  __syncthreads();

  for (int jc = tid; jc < 352; jc += 256) {
    bf16x8 o8;
    #pragma unroll
    for (int e = 0; e < 8; ++e) {
      int j = jc * 8 + e;
      float v;
      if (j < i)            v = vals[j] * inv;
      else if (j == i)      v = 0.f;
      else if (j < AREAL)   v = vals[j - 1] * inv;
      else                  v = 0.f;
      o8[e] = f2bf(v);
    }
    *(bf16x8*)(row + jc * 8) = o8;
  }
}

// ---------------- N=80 GEMM core (plain A load), 2-phase dbuf
__device__ __forceinline__
void gemm_n80_body(const short* __restrict__ abase, int ald, int m0,
                   const short* __restrict__ hb, int ldbh,
                   short* __restrict__ lp, int nk,
                   short* lds_a, short* lds_b)
{
  int tid = threadIdx.x, lane = tid & 63, wid = tid >> 6;

  floatx4 acc[2][5];
  #pragma unroll
  for (int m = 0; m < 2; ++m)
    #pragma unroll
    for (int n = 0; n < 5; ++n) acc[m][n] = floatx4{0.f, 0.f, 0.f, 0.f};

  bf16x8 ra[2], rb0, rb1, xa[2], xb0, xb1;
  bool has2 = (tid < 64);

  auto stage_load = [&](int kt, bf16x8* r_a, bf16x8& r_b0, bf16x8& r_b1) {
    int kk = kt * 32;
    #pragma unroll
    for (int it = 0; it < 2; ++it) {
      int rw = it * 64 + (tid >> 2);
      int ks = (tid & 3) ^ ((rw >> 1) & 3);
      r_a[it] = *(const bf16x8*)(abase + (long)(m0 + rw) * ald + kk + ks * 8);
    }
    {
      int n = tid >> 2;
      int ks = (tid & 3) ^ ((n >> 1) & 3);
      r_b0 = *(const bf16x8*)(hb + (long)n * ldbh + kk + ks * 8);
    }
    if (has2) {
      int n = (tid + 256) >> 2;
      int ks = (tid & 3) ^ ((n >> 1) & 3);
      r_b1 = *(const bf16x8*)(hb + (long)n * ldbh + kk + ks * 8);
    }
  };
  auto stage_write = [&](int buf, bf16x8* r_a, bf16x8& r_b0, bf16x8& r_b1) {
    char* la = (char*)lds_a + buf * 8192;
    char* lb = (char*)lds_b + buf * 8192;
    #pragma unroll
    for (int it = 0; it < 2; ++it) {
      int rw = it * 64 + (tid >> 2);
      *(bf16x8*)(la + rw * 64 + ((tid & 3) << 4)) = r_a[it];
    }
    { int n = tid >> 2;
      *(bf16x8*)(lb + n * 64 + ((tid & 3) << 4)) = r_b0; }
    if (has2) {
      int n = (tid + 256) >> 2;
      *(bf16x8*)(lb + n * 64 + ((tid & 3) << 4)) = r_b1;
    }
  };

  stage_load(0, ra, rb0, rb1);
  stage_write(0, ra, rb0, rb1);
  __syncthreads();
  int cur = 0;
  for (int kt = 0; kt < nk; ++kt) {
    bool more = (kt + 1 < nk);
    if (more) stage_load(kt + 1, xa, xb0, xb1);
    const char* la = (const char*)lds_a + cur * 8192;
    const char* lb = (const char*)lds_b + cur * 8192;
    bf16x8 af[2], bfv[5];
    #pragma unroll
    for (int m = 0; m < 2; ++m) {
      int rw = wid * 32 + m * 16 + (lane & 15);
      int pp = (lane >> 4) ^ ((rw >> 1) & 3);
      af[m] = *(const bf16x8*)(la + rw * 64 + (pp << 4));
    }
    #pragma unroll
    for (int n = 0; n < 5; ++n) {
      int nn = n * 16 + (lane & 15);
      int pp = (lane >> 4) ^ ((nn >> 1) & 3);
      bfv[n] = *(const bf16x8*)(lb + nn * 64 + (pp << 4));
    }
    #pragma unroll
    for (int m = 0; m < 2; ++m)
      #pragma unroll
      for (int n = 0; n < 5; ++n)
        acc[m][n] = __builtin_amdgcn_mfma_f32_16x16x32_bf16(af[m], bfv[n], acc[m][n], 0, 0, 0);
    if (more) stage_write(cur ^ 1, xa, xb0, xb1);
    __syncthreads();
    cur ^= 1;
  }

  #pragma unroll
  for (int fm = 0; fm < 2; ++fm)
    #pragma unroll
    for (int fn = 0; fn < 5; ++fn)
      #pragma unroll
      for (int rr = 0; rr < 4; ++rr) {
        int rw = m0 + wid * 32 + fm * 16 + (lane >> 4) * 4 + rr;
        int col = fn * 16 + (lane & 15);
        lp[(long)rw * NH + col] = f2bf(acc[fm][fn][rr]);
      }
}

// ---------------- N=80 GEMM core with GATHERED A (past chunks from feats via gidx)
__device__ __forceinline__
void gemm_n80_gather_body(const short* __restrict__ fp, const int* __restrict__ gidx,
                          int m0, const short* __restrict__ hb,
                          short* __restrict__ lp,
                          short* lds_a, short* lds_b)
{
  int tid = threadIdx.x, lane = tid & 63, wid = tid >> 6;

  floatx4 acc[2][5];
  #pragma unroll
  for (int m = 0; m < 2; ++m)
    #pragma unroll
    for (int n = 0; n < 5; ++n) acc[m][n] = floatx4{0.f, 0.f, 0.f, 0.f};

  bf16x8 ra[2], rb0, rb1, xa[2], xb0, xb1;
  bool has2 = (tid < 64);

  auto stage_load = [&](int kt, bf16x8* r_a, bf16x8& r_b0, bf16x8& r_b1) {
    #pragma unroll
    for (int it = 0; it < 2; ++it) {
      int rw = it * 64 + (tid >> 2);
      int a = m0 + rw;
      int ks = (tid & 3) ^ ((rw >> 1) & 3);
      int d0 = kt * 32 + ks * 8;
      bf16x8 v = {};
      if (a < AREAL) {
        #pragma unroll
        for (int e = 0; e < 8; ++e) {
          int d = d0 + e;
          int o = d / 11;
          int hh = d - o * 11;
          int gi = gidx[a * 11 + hh];
          v[e] = (gi < 0) ? (short)0 : fp[gi + o];
        }
      }
      r_a[it] = v;
    }
    int kk = kt * 32;
    {
      int n = tid >> 2;
      int ks = (tid & 3) ^ ((n >> 1) & 3);
      r_b0 = *(const bf16x8*)(hb + (long)n * KH + kk + ks * 8);
    }
    if (has2) {
      int n = (tid + 256) >> 2;
      int ks = (tid & 3) ^ ((n >> 1) & 3);
      r_b1 = *(const bf16x8*)(hb + (long)n * KH + kk + ks * 8);
    }
  };
  auto stage_write = [&](int buf, bf16x8* r_a, bf16x8& r_b0, bf16x8& r_b1) {
    char* la = (char*)lds_a + buf * 8192;
    char* lb = (char*)lds_b + buf * 8192;
    #pragma unroll
    for (int it = 0; it < 2; ++it) {
      int rw = it * 64 + (tid >> 2);
      *(bf16x8*)(la + rw * 64 + ((tid & 3) << 4)) = r_a[it];
    }
    { int n = tid >> 2;
      *(bf16x8*)(lb + n * 64 + ((tid & 3) << 4)) = r_b0; }
    if (has2) {
      int n = (tid + 256) >> 2;
      *(bf16x8*)(lb + n * 64 + ((tid & 3) << 4)) = r_b1;
    }
  };

  const int nk = 22;
  stage_load(0, ra, rb0, rb1);
  stage_write(0, ra, rb0, rb1);
  __syncthreads();
  int cur = 0;
  for (int kt = 0; kt < nk; ++kt) {
    bool more = (kt + 1 < nk);
    if (more) stage_load(kt + 1, xa, xb0, xb1);
    const char* la = (const char*)lds_a + cur * 8192;
    const char* lb = (const char*)lds_b + cur * 8192;
    bf16x8 af[2], bfv[5];
    #pragma unroll
    for (int m = 0; m < 2; ++m) {
      int rw = wid * 32 + m * 16 + (lane & 15);
      int pp = (lane >> 4) ^ ((rw >> 1) & 3);
      af[m] = *(const bf16x8*)(la + rw * 64 + (pp << 4));
    }
    #pragma unroll
    for (int n = 0; n < 5; ++n) {
      int nn = n * 16 + (lane & 15);
      int pp = (lane >> 4) ^ ((nn >> 1) & 3);
      bfv[n] = *(const bf16x8*)(lb + nn * 64 + (pp << 4));
    }
    #pragma unroll
    for (int m = 0; m < 2; ++m)
      #pragma unroll
      for (int n = 0; n < 5; ++n)
        acc[m][n] = __builtin_amdgcn_mfma_f32_16x16x32_bf16(af[m], bfv[n], acc[m][n], 0, 0, 0);
    if (more) stage_write(cur ^ 1, xa, xb0, xb1);
    __syncthreads();
    cur ^= 1;
  }

  #pragma unroll
  for (int fm = 0; fm < 2; ++fm)
    #pragma unroll
    for (int fn = 0; fn < 5; ++fn)
      #pragma unroll
      for (int rr = 0; rr < 4; ++rr) {
        int rw = m0 + wid * 32 + fm * 16 + (lane >> 4) * 4 + rr;
        int col = fn * 16 + (lane & 15);
        lp[(long)rw * NH + col] = f2bf(acc[fm][fn][rr]);
      }
}

// ---------------- tail GEMM: kc 0..2 past(gathered), 3 cur, 4..7 skinny K-partials
__global__ __launch_bounds__(256)
void gemm_tail_kernel(const short* __restrict__ fpo_base, const int* __restrict__ gidx,
                      const short* __restrict__ curR, const short* __restrict__ scores,
                      const short* __restrict__ curW3T, const short* __restrict__ headwT,
                      short* __restrict__ linpart, int G)
{
  int kc = blockIdx.x;        // 0..7
  int m0 = blockIdx.y * 128;
  int g  = blockIdx.z;
  __shared__ short lds_a[2 * 128 * 32];
  __shared__ short lds_b[2 * 128 * 32];
  short* lp = linpart + (long)(kc * G + g) * AP * NH;

  if (kc < 3) {
    const short* fp = fpo_base + ((long)g * TT + kc) * PPAD * 128;
    gemm_n80_gather_body(fp, gidx, m0, headwT + kc * DD, lp, lds_a, lds_b);
  } else if (kc == 3) {
    gemm_n80_body(curR + (long)g * AP * DD, DD, m0, headwT + 4 * DD, KH, lp,
                  DD / 32, lds_a, lds_b);
  } else {
    int c = kc - 4;
    gemm_n80_body(scores + (long)g * AP * AP + (long)c * 704, AP, m0,
                  curW3T + (long)g * NHP * AP + (long)c * 704, AP, lp,
                  704 / 32, lds_a, lds_b);
  }
}

// ---------------- assemble G batches: out[g][a][c], summing 8 bf16 K-partials
__global__ void assemble_kernel(const short* __restrict__ linpart, const float* __restrict__ anchors,
                                const float* __restrict__ cls_b, const float* __restrict__ reg_b,
                                float* __restrict__ out_b0, int G)
{
  long idx = (long)blockIdx.x * 256 + threadIdx.x;
  const long per_g = (long)AREAL * 77;
  if (idx >= per_g * G) return;
  int g = (int)(idx / per_g);
  long rem = idx - (long)g * per_g;
  int c = (int)(rem % 77);
  int a = (int)(rem / 77);
  float v;
  if (c == 2) {
    v = anchors[(long)a * 77 + 2];
  } else {
    int col = (c < 2) ? c : (2 + (c - 3));
    float s = 0.f;
    #pragma unroll
    for (int sl = 0; sl < 8; ++sl)
      s += bf2f(linpart[((long)(sl * G + g) * AP + a) * NH + col]);
    v = (c < 2) ? (s + cls_b[c]) : (anchors[(long)a * 77 + c] + s + reg_b[c - 3]);
  }
  out_b0[idx] = v;
}

extern "C" void kernel_launch(void* const* d_in, const int* in_sizes, int n_in,
                              void* d_out, int out_size, void* d_ws, size_t ws_size,
                              hipStream_t stream)
{
  (void)in_sizes; (void)n_in; (void)out_size;
  const float* x        = (const float*)d_in[0];
  const float* conv1_w  = (const float*)d_in[1];
  const float* conv1_b  = (const float*)d_in[2];
  const float* att_w    = (const float*)d_in[3];
  const float* att_b    = (const float*)d_in[4];
  const float* cls_w    = (const float*)d_in[5];
  const float* cls_b    = (const float*)d_in[6];
  const float* reg_w    = (const float*)d_in[7];
  const float* reg_b    = (const float*)d_in[8];
  const float* anchors  = (const float*)d_in[9];
  const int*   cut_xs   = (const int*)d_in[10];
  const int*   invalid  = (const int*)d_in[11];
  float* out = (float*)d_out;

  auto align256 = [](size_t v) { return (v + 255) & ~(size_t)255; };
  const size_t sz_feats  = align256((size_t)BB * TT * PPAD * 128 * 2);
  const size_t sz_wbf    = align256((size_t)128 * CIN * 2);
  const size_t sz_attwT  = align256((size_t)AP * DD * 2);
  const size_t sz_headwT = align256((size_t)NHP * KH * 2);
  const size_t sz_gidx   = align256((size_t)AREAL * HH * 4);
  const size_t misc = sz_feats + sz_wbf + sz_attwT + sz_headwT + sz_gidx;
  auto per_g = [&](int G) {
    return align256((size_t)G * AP * DD * 2)      // curR
         + align256((size_t)G * AP * AP * 2)      // scores (hosts xT)
         + align256((size_t)G * NHP * AP * 2)     // curW3T
         + align256((size_t)8 * G * AP * NH * 2); // linpart (8 slots)
  };
  int G = 1;
  for (int cand : {8, 4, 2}) {
    if (misc + per_g(cand) + (1u << 20) <= ws_size) { G = cand; break; }
  }

  char* p = (char*)d_ws;
  short* feats_po = (short*)p; p += sz_feats;
  short* w_bf16   = (short*)p; p += sz_wbf;
  short* attwT    = (short*)p; p += sz_attwT;
  short* headwT   = (short*)p; p += sz_headwT;
  int*   gidx     = (int*)p;   p += sz_gidx;
  short* curR     = (short*)p; p += align256((size_t)G * AP * DD * 2);
  short* scores   = (short*)p; p += align256((size_t)G * AP * AP * 2);
  short* curW3T   = (short*)p; p += align256((size_t)G * NHP * AP * 2);
  short* linpart  = (short*)p; p += align256((size_t)8 * G * AP * NH * 2);
  short* xT       = scores;               // 8.39 MB <= G*15.86 MB

  transpose_x_kernel<<<dim3(BB * TT, CIN / 32), 256, 0, stream>>>(x, xT);
  prep_wbf_kernel<<<(128 * CIN + 255) / 256, 256, 0, stream>>>(conv1_w, w_bf16);
  prep_attw_kernel<<<dim3(AP / 32, DD / 32), 256, 0, stream>>>(att_w, attwT);
  prep_headw_kernel<<<(NHP * KH + 255) / 256, 256, 0, stream>>>(cls_w, reg_w, headwT);
  prep_gidx_kernel<<<(AREAL * HH + 255) / 256, 256, 0, stream>>>(cut_xs, invalid, gidx);

  // conv as GEMM: feats_po[bt*256+p][o]
  gemm_nt_kernel<1><<<dim3(1, BB * TT * PPAD / 128, 1), 256, 0, stream>>>(
      xT, 0, CIN, w_bf16, 0, CIN, feats_po, 0, 128, CIN, conv1_b, CAF);

  for (int b0 = 0; b0 < BB; b0 += G) {
    const short* fpo = feats_po + (long)b0 * TT * PPAD * 128;

    gather_cur_kernel<<<dim3(AP * 88 / 256, G), 256, 0, stream>>>(fpo, gidx, curR);

    // scores = cur @ attwT^T + att_b  — flattened GEMM: M = G*AP, 256² deep
    gemm256_nt_kernel<<<dim3(AP / 256, G * AP / 256, 1), 512, 0, stream>>>(
        curR, 0, DD, attwT, 0, DD, scores, 0, AP, DD, att_b, NATT);

    softmax_shift_kernel<<<dim3(AREAL, G), 256, 0, stream>>>(scores);

    // curW3T[g][n][j] = sum_d headwT[n][2112+d] * curR[g][j][d]
    gemm_nt_kernel<0><<<dim3(AP / 128, 1, G), 256, 0, stream>>>(
        headwT + 3 * DD, 0, KH, curR, (long long)AP * DD, DD,
        curW3T, (long long)NHP * AP, AP, DD, nullptr, 0);

    // tail: slots 0..3 heads chunks, 4..7 skinny K-partials — ONE launch
    gemm_tail_kernel<<<dim3(8, AP / 128, G), 256, 0, stream>>>(
        fpo, gidx, curR, scores, curW3T, headwT, linpart, G);

    assemble_kernel<<<(int)(((long)G * AREAL * 77 + 255) / 256), 256, 0, stream>>>(
        linpart, anchors, cls_b, reg_b, out + (long)b0 * AREAL * 77, G);
  }
}

// Round 12
// 379.607 us; speedup vs baseline: 1.2273x; 1.2273x over previous
//
#include <hip/hip_runtime.h>

#define BB 8
#define TT 4
#define CIN 512
#define CAF 64
#define HH 11
#define WW 20
#define PP 220           // H*W positions
#define PPAD 256
#define AREAL 2784
#define AP 2816          // padded anchors
#define DD 704           // C_AF*H
#define NH 80            // padded head cols (2 cls + 74 reg)
#define NHP 128          // padded head rows for B-staging
#define KH 3520          // 5*DD
#define NATT 2783        // A-1

typedef __attribute__((ext_vector_type(8))) short bf16x8;
typedef __attribute__((ext_vector_type(4))) float floatx4;

__device__ __forceinline__ short f2bf(float f) {
  unsigned u = __float_as_uint(f);
  u += 0x7fffu + ((u >> 16) & 1u);
  return (short)(u >> 16);
}
__device__ __forceinline__ float bf2f(short s) {
  return __uint_as_float(((unsigned)(unsigned short)s) << 16);
}

__device__ __forceinline__ void gload_lds16(const void* g, void* l) {
  __builtin_amdgcn_global_load_lds(
      (const __attribute__((address_space(1))) void*)g,
      (__attribute__((address_space(3))) void*)l, 16, 0, 0);
}

// ---------------- xT[bt][p(256)][c(512)] = bf16(x[bt][c][p]), p>=220 -> 0
__global__ __launch_bounds__(256)
void transpose_x_kernel(const float* __restrict__ x, short* __restrict__ xT)
{
  int bt = blockIdx.x;        // 0..31
  int c0 = blockIdx.y * 32;   // 0..480
  __shared__ float xs[32 * PP];
  int tid = threadIdx.x;
  const float* xp = x + ((long)bt * CIN + c0) * PP;
  for (int i = tid; i < 32 * PP; i += 256) xs[i] = xp[i];
  __syncthreads();
  short* op = xT + (long)bt * PPAD * CIN + c0;
  for (int j = tid; j < PPAD * 32; j += 256) {
    int p = j >> 5, cc = j & 31;
    short v = 0;
    if (p < PP) v = f2bf(xs[cc * PP + p]);
    op[(long)p * CIN + cc] = v;
  }
}

// ---------------- w_bf16[n(128)][c(512)]: n<64 -> conv1_w[n][c], else 0
__global__ void prep_wbf_kernel(const float* __restrict__ w, short* __restrict__ wb)
{
  int idx = blockIdx.x * 256 + threadIdx.x;
  if (idx >= 128 * CIN) return;
  int n = idx >> 9, c = idx & 511;
  wb[idx] = (n < CAF) ? f2bf(w[(long)n * CIN + c]) : (short)0;
}

// ---------------- gidx[a][hh] = invalid ? -1 : (hh*20+xw)*128
__global__ void prep_gidx_kernel(const int* __restrict__ cut_xs, const int* __restrict__ invalid,
                                 int* __restrict__ gidx)
{
  int idx = blockIdx.x * 256 + threadIdx.x;
  if (idx >= AREAL * HH) return;
  int hh = idx % HH;
  gidx[idx] = invalid[idx] ? -1 : (hh * WW + cut_xs[idx]) * 128;
}

// ---------------- gather cur (t=3), d-major vectorized
__global__ __launch_bounds__(256)
void gather_cur_kernel(const short* __restrict__ fpo_base, const int* __restrict__ gidx,
                       short* __restrict__ curR)
{
  int g = blockIdx.y;
  int idx = blockIdx.x * 256 + threadIdx.x;   // over AP*88
  int a = idx / 88;
  int ch = idx - a * 88;
  int d0 = ch * 8;
  bf16x8 v = {};
  if (a < AREAL) {
    const short* fp = fpo_base + ((long)g * TT + 3) * PPAD * 128;
    #pragma unroll
    for (int e = 0; e < 8; ++e) {
      int d = d0 + e;
      int o = d / 11;
      int hh = d - o * 11;
      int gi = gidx[a * 11 + hh];
      v[e] = (gi < 0) ? (short)0 : fp[gi + o];
    }
  }
  *(bf16x8*)(curR + ((long)g * AP + a) * DD + d0) = v;
}

// ---------------- gather past (t=0..2), d-major vectorized
__global__ __launch_bounds__(256)
void gather_past_kernel(const short* __restrict__ fpo_base, const int* __restrict__ gidx,
                        short* __restrict__ pastR)
{
  int ty = blockIdx.y;            // g*3 + t
  int g = ty / 3, t = ty - g * 3;
  int idx = blockIdx.x * 256 + threadIdx.x;   // over AP*88
  int a = idx / 88;
  int ch = idx - a * 88;
  int d0 = ch * 8;
  bf16x8 v = {};
  if (a < AREAL) {
    const short* fp = fpo_base + ((long)g * TT + t) * PPAD * 128;
    #pragma unroll
    for (int e = 0; e < 8; ++e) {
      int d = d0 + e;
      int o = d / 11;
      int hh = d - o * 11;
      int gi = gidx[a * 11 + hh];
      v[e] = (gi < 0) ? (short)0 : fp[gi + o];
    }
  }
  *(bf16x8*)(pastR + ((long)ty * AP + a) * DD + d0) = v;
}

// ---------------- attw_T[n][d] = att_w[d][n] bf16 (pad -> 0)
__global__ __launch_bounds__(256)
void prep_attw_kernel(const float* __restrict__ att_w, short* __restrict__ attwT)
{
  int n0 = blockIdx.x * 32;
  int d0 = blockIdx.y * 32;
  __shared__ float tile[32][33];
  int tid = threadIdx.x;
  for (int i = tid; i < 1024; i += 256) {
    int r = i >> 5, c = i & 31;
    int d = d0 + r, n = n0 + c;
    tile[r][c] = (d < DD && n < NATT) ? att_w[(long)d * NATT + n] : 0.f;
  }
  __syncthreads();
  for (int i = tid; i < 1024; i += 256) {
    int r = i >> 5, c = i & 31;
    attwT[(long)(n0 + r) * DD + d0 + c] = f2bf(tile[c][r]);
  }
}

// ---------------- headwT[n(128)][k]: n<2 cls_w[k][n]; 2<=n<76 reg_w[k][n-2]; else 0
__global__ void prep_headw_kernel(const float* __restrict__ cls_w, const float* __restrict__ reg_w,
                                  short* __restrict__ headwT)
{
  long idx = (long)blockIdx.x * 256 + threadIdx.x;
  if (idx >= (long)NHP * KH) return;
  int n = (int)(idx / KH), k = (int)(idx % KH);
  float v = 0.f;
  if (n < 2) v = cls_w[(long)k * 2 + n];
  else if (n < 76) v = reg_w[(long)k * 74 + (n - 2)];
  headwT[idx] = f2bf(v);
}

// ================= 256x256 deep-pipelined NT GEMM (round-8 schedule) =================
__global__ __launch_bounds__(512, 2)
void gemm256_nt_kernel(const short* __restrict__ A, long long aBatch, int lda,
                       const short* __restrict__ Bt, long long bBatch, int ldb,
                       short* __restrict__ C, long long cBatch, int ldc,
                       int K, const float* __restrict__ bias, int biasN)
{
  int gx = gridDim.x, gy = gridDim.y;
  int nwg = gx * gy * gridDim.z;
  int o = blockIdx.x + gx * (blockIdx.y + gy * blockIdx.z);
  int xcd = o & 7, pos = o >> 3;
  int q = nwg >> 3, r = nwg & 7;
  int nid = (xcd < r ? xcd * (q + 1) : r * (q + 1) + (xcd - r) * q) + pos;
  int bx = nid % gx; int tq = nid / gx; int by = tq % gy; int bz = tq / gy;

  A  += (long long)bz * aBatch;
  Bt += (long long)bz * bBatch;
  C  += (long long)bz * cBatch;
  int M0 = by * 256, N0 = bx * 256;

  __shared__ short lds_a[2 * 256 * 64];
  __shared__ short lds_b[2 * 256 * 64];

  int tid = threadIdx.x, lane = tid & 63, w = tid >> 6;
  int wr = w >> 2, wc = w & 3;

  floatx4 acc[8][4];
  #pragma unroll
  for (int m = 0; m < 8; ++m)
    #pragma unroll
    for (int n = 0; n < 4; ++n) acc[m][n] = floatx4{0.f, 0.f, 0.f, 0.f};

  int rl = tid >> 3, sl = tid & 7;
  int ssl = sl ^ (rl & 7);
  const short* aS = A  + (long)(M0 + rl) * lda + ssl * 8;
  const short* bS = Bt + (long)(N0 + rl) * ldb + ssl * 8;
  char* la0 = (char*)lds_a;
  char* lb0 = (char*)lds_b;
  int wub = (tid & ~63) * 16;

  auto stage = [&](int kt, int buf) {
    long ko = (long)kt * 64;
    #pragma unroll
    for (int c = 0; c < 4; ++c) {
      gload_lds16(aS + (long)c * 64 * lda + ko, la0 + buf * 32768 + c * 8192 + wub);
      gload_lds16(bS + (long)c * 64 * ldb + ko, lb0 + buf * 32768 + c * 8192 + wub);
    }
  };
  auto rdA = [&](int buf, int mf, int kk) -> bf16x8 {
    int row = wr * 128 + mf * 16 + (lane & 15);
    int phys = (kk * 4 + (lane >> 4)) ^ (lane & 7);
    return *(const bf16x8*)(la0 + buf * 32768 + row * 128 + phys * 16);
  };
  auto rdB = [&](int buf, int nf, int kk) -> bf16x8 {
    int row = wc * 64 + nf * 16 + (lane & 15);
    int phys = (kk * 4 + (lane >> 4)) ^ (lane & 7);
    return *(const bf16x8*)(lb0 + buf * 32768 + row * 128 + phys * 16);
  };

  int nt = K >> 6;
  stage(0, 0);
  stage(1, 1);
  asm volatile("s_waitcnt vmcnt(8)" ::: "memory");
  __builtin_amdgcn_sched_barrier(0);
  __builtin_amdgcn_s_barrier();
  __builtin_amdgcn_sched_barrier(0);

  for (int t = 0; t < nt; ++t) {
    int buf = t & 1;
    bf16x8 A0[2][4], A1[2][4], B0[2][2], B1[2][2];
    #pragma unroll
    for (int kk = 0; kk < 2; ++kk) {
      #pragma unroll
      for (int i = 0; i < 4; ++i) A0[kk][i] = rdA(buf, i, kk);
      #pragma unroll
      for (int j = 0; j < 2; ++j) B0[kk][j] = rdB(buf, j, kk);
    }
    __builtin_amdgcn_s_setprio(1);
    #pragma unroll
    for (int kk = 0; kk < 2; ++kk)
      #pragma unroll
      for (int i = 0; i < 4; ++i)
        #pragma unroll
        for (int j = 0; j < 2; ++j)
          acc[i][j] = __builtin_amdgcn_mfma_f32_16x16x32_bf16(A0[kk][i], B0[kk][j], acc[i][j], 0, 0, 0);
    __builtin_amdgcn_s_setprio(0);
    #pragma unroll
    for (int kk = 0; kk < 2; ++kk)
      #pragma unroll
      for (int j = 0; j < 2; ++j) B1[kk][j] = rdB(buf, 2 + j, kk);
    __builtin_amdgcn_s_setprio(1);
    #pragma unroll
    for (int kk = 0; kk < 2; ++kk)
      #pragma unroll
      for (int i = 0; i < 4; ++i)
        #pragma unroll
        for (int j = 0; j < 2; ++j)
          acc[i][2 + j] = __builtin_amdgcn_mfma_f32_16x16x32_bf16(A0[kk][i], B1[kk][j], acc[i][2 + j], 0, 0, 0);
    __builtin_amdgcn_s_setprio(0);
    #pragma unroll
    for (int kk = 0; kk < 2; ++kk)
      #pragma unroll
      for (int i = 0; i < 4; ++i) A1[kk][i] = rdA(buf, 4 + i, kk);
    __builtin_amdgcn_s_setprio(1);
    #pragma unroll
    for (int kk = 0; kk < 2; ++kk)
      #pragma unroll
      for (int i = 0; i < 4; ++i)
        #pragma unroll
        for (int j = 0; j < 2; ++j)
          acc[4 + i][2 + j] = __builtin_amdgcn_mfma_f32_16x16x32_bf16(A1[kk][i], B1[kk][j], acc[4 + i][2 + j], 0, 0, 0);
    __builtin_amdgcn_s_setprio(0);
    __builtin_amdgcn_sched_barrier(0);
    __builtin_amdgcn_s_barrier();
    __builtin_amdgcn_sched_barrier(0);
    if (t + 2 < nt) stage(t + 2, buf);
    __builtin_amdgcn_s_setprio(1);
    #pragma unroll
    for (int kk = 0; kk < 2; ++kk)
      #pragma unroll
      for (int i = 0; i < 4; ++i)
        #pragma unroll
        for (int j = 0; j < 2; ++j)
          acc[4 + i][j] = __builtin_amdgcn_mfma_f32_16x16x32_bf16(A1[kk][i], B0[kk][j], acc[4 + i][j], 0, 0, 0);
    __builtin_amdgcn_s_setprio(0);
    if (t + 2 < nt) {
      asm volatile("s_waitcnt vmcnt(8)" ::: "memory");
    } else {
      asm volatile("s_waitcnt vmcnt(0)" ::: "memory");
    }
    __builtin_amdgcn_sched_barrier(0);
    __builtin_amdgcn_s_barrier();
    __builtin_amdgcn_sched_barrier(0);
  }

  #pragma unroll
  for (int mf = 0; mf < 8; ++mf) {
    #pragma unroll
    for (int nf = 0; nf < 4; ++nf) {
      int col = N0 + wc * 64 + nf * 16 + (lane & 15);
      float bv = 0.f;
      if (bias) bv = (col < biasN) ? bias[col] : 0.f;
      #pragma unroll
      for (int rr = 0; rr < 4; ++rr) {
        int rowc = M0 + wr * 128 + mf * 16 + (lane >> 4) * 4 + rr;
        C[(long)rowc * ldc + col] = f2bf(acc[mf][nf][rr] + bv);
      }
    }
  }
}

// ---------------- batched NT GEMM: 128x128 tile, 2-phase dbuf (conv + curW3T)
template<int WITH_BIAS>
__global__ __launch_bounds__(256)
void gemm_nt_kernel(const short* __restrict__ A, long long aBatch, int lda,
                    const short* __restrict__ Bt, long long bBatch, int ldb,
                    short* __restrict__ C, long long cBatch, int ldc,
                    int K, const float* __restrict__ bias, int biasN)
{
  int gx = gridDim.x, gy = gridDim.y;
  int nwg = gx * gy * gridDim.z;
  int o = blockIdx.x + gx * (blockIdx.y + gy * blockIdx.z);
  int xcd = o & 7, pos = o >> 3;
  int q = nwg >> 3, r = nwg & 7;
  int nid = (xcd < r ? xcd * (q + 1) : r * (q + 1) + (xcd - r) * q) + pos;
  int bx = nid % gx; int t = nid / gx; int by = t % gy; int bz = t / gy;

  A  += (long long)bz * aBatch;
  Bt += (long long)bz * bBatch;
  C  += (long long)bz * cBatch;
  int m0 = by * 128;
  int n0 = bx * 128;

  __shared__ short lds_a[2 * 128 * 32];
  __shared__ short lds_b[2 * 128 * 32];

  int tid = threadIdx.x;
  int lane = tid & 63;
  int wid = tid >> 6;
  int wr = wid >> 1, wc = wid & 1;
  int row = tid >> 2;
  int slot = tid & 3;

  floatx4 acc[4][4];
  #pragma unroll
  for (int m = 0; m < 4; ++m)
    #pragma unroll
    for (int n = 0; n < 4; ++n) acc[m][n] = floatx4{0.f, 0.f, 0.f, 0.f};

  int wbase = (tid & ~63) * 16;
  int ks0 = slot ^ ((row >> 1) & 3);
  int ks1 = slot ^ (((row + 64) >> 1) & 3);
  const short* ar0 = A  + (long)(m0 + row) * lda + ks0 * 8;
  const short* ar1 = A  + (long)(m0 + row + 64) * lda + ks1 * 8;
  const short* br0 = Bt + (long)(n0 + row) * ldb + ks0 * 8;
  const short* br1 = Bt + (long)(n0 + row + 64) * ldb + ks1 * 8;

  auto stage = [&](int kt, int buf) {
    int k0 = kt * 32;
    char* la = (char*)lds_a + buf * 8192 + wbase;
    char* lb = (char*)lds_b + buf * 8192 + wbase;
    gload_lds16(ar0 + k0, la);
    gload_lds16(ar1 + k0, la + 4096);
    gload_lds16(br0 + k0, lb);
    gload_lds16(br1 + k0, lb + 4096);
  };

  int nk = K >> 5;
  stage(0, 0);
  __syncthreads();
  int cur = 0;
  for (int kt = 0; kt < nk; ++kt) {
    if (kt + 1 < nk) stage(kt + 1, cur ^ 1);
    const char* ba = (const char*)lds_a + cur * 8192;
    const char* bb = (const char*)lds_b + cur * 8192;
    bf16x8 af[4], bfv[4];
    #pragma unroll
    for (int m = 0; m < 4; ++m) {
      int rw = wr * 64 + m * 16 + (lane & 15);
      int pp = (lane >> 4) ^ ((rw >> 1) & 3);
      af[m] = *(const bf16x8*)(ba + rw * 64 + (pp << 4));
    }
    #pragma unroll
    for (int n = 0; n < 4; ++n) {
      int rw = wc * 64 + n * 16 + (lane & 15);
      int pp = (lane >> 4) ^ ((rw >> 1) & 3);
      bfv[n] = *(const bf16x8*)(bb + rw * 64 + (pp << 4));
    }
    #pragma unroll
    for (int m = 0; m < 4; ++m)
      #pragma unroll
      for (int n = 0; n < 4; ++n)
        acc[m][n] = __builtin_amdgcn_mfma_f32_16x16x32_bf16(af[m], bfv[n], acc[m][n], 0, 0, 0);
    __syncthreads();
    cur ^= 1;
  }

  #pragma unroll
  for (int m = 0; m < 4; ++m) {
    #pragma unroll
    for (int n = 0; n < 4; ++n) {
      int col = n0 + wc * 64 + n * 16 + (lane & 15);
      float bv = 0.f;
      if (WITH_BIAS) bv = (col < biasN) ? bias[col] : 0.f;
      #pragma unroll
      for (int rr = 0; rr < 4; ++rr) {
        int rowc = m0 + wr * 64 + m * 16 + (lane >> 4) * 4 + rr;
        C[(long)rowc * ldc + col] = f2bf(acc[m][n][rr] + bv);
      }
    }
  }
}

// ---------------- per-row softmax + shifted M-row write in place (vectorized)
__global__ __launch_bounds__(256)
void softmax_shift_kernel(short* __restrict__ scores)
{
  int g = blockIdx.y;
  int i = blockIdx.x;   // 0..2783
  short* row = scores + (long)g * AP * AP + (long)i * AP;
  __shared__ float vals[NATT];
  __shared__ float red[4];
  int tid = threadIdx.x;

  float lmax = -1e30f;
  for (int jc = tid; jc < 348; jc += 256) {
    bf16x8 v8 = *(const bf16x8*)(row + jc * 8);
    #pragma unroll
    for (int e = 0; e < 8; ++e) {
      int j = jc * 8 + e;
      float f = bf2f(v8[e]);
      if (j < NATT) { vals[j] = f; lmax = fmaxf(lmax, f); }
    }
  }
  #pragma unroll
  for (int off = 32; off; off >>= 1) lmax = fmaxf(lmax, __shfl_down(lmax, off, 64));
  if ((tid & 63) == 0) red[tid >> 6] = lmax;
  __syncthreads();
  float mx = fmaxf(fmaxf(red[0], red[1]), fmaxf(red[2], red[3]));
  __syncthreads();

  float lsum = 0.f;
  for (int j = tid; j < NATT; j += 256) {
    float e = __expf(vals[j] - mx);
    vals[j] = e;
    lsum += e;
  }
  #pragma unroll
  for (int off = 32; off; off >>= 1) lsum += __shfl_down(lsum, off, 64);
  if ((tid & 63) == 0) red[tid >> 6] = lsum;
  __syncthreads();
  float inv = 1.f / (red[0] + red[1] + red[2] + red[3]);
  __syncthreads();

  for (int jc = tid; jc < 352; jc += 256) {
    bf16x8 o8;
    #pragma unroll
    for (int e = 0; e < 8; ++e) {
      int j = jc * 8 + e;
      float v;
      if (j < i)            v = vals[j] * inv;
      else if (j == i)      v = 0.f;
      else if (j < AREAL)   v = vals[j - 1] * inv;
      else                  v = 0.f;
      o8[e] = f2bf(v);
    }
    *(bf16x8*)(row + jc * 8) = o8;
  }
}

// ---------------- N=80 GEMM core: gload_lds staging (A 128 rows, B 128 rows), 2-phase dbuf
__device__ __forceinline__
void gemm_n80_body(const short* __restrict__ abase, int ald, int m0,
                   const short* __restrict__ hb, int ldbh,
                   short* __restrict__ lp, int nk,
                   short* lds_a, short* lds_b)
{
  int tid = threadIdx.x, lane = tid & 63, wid = tid >> 6;

  floatx4 acc[2][5];
  #pragma unroll
  for (int m = 0; m < 2; ++m)
    #pragma unroll
    for (int n = 0; n < 5; ++n) acc[m][n] = floatx4{0.f, 0.f, 0.f, 0.f};

  int wbase = (tid & ~63) * 16;
  int row = tid >> 2;
  int slot = tid & 3;
  int ks0 = slot ^ ((row >> 1) & 3);
  int ks1 = slot ^ (((row + 64) >> 1) & 3);
  const short* ar0 = abase + (long)(m0 + row) * ald + ks0 * 8;
  const short* ar1 = abase + (long)(m0 + row + 64) * ald + ks1 * 8;
  const short* br0 = hb + (long)row * ldbh + ks0 * 8;
  const short* br1 = hb + (long)(row + 64) * ldbh + ks1 * 8;

  auto stage = [&](int kt, int buf) {
    int k0 = kt * 32;
    char* la = (char*)lds_a + buf * 8192 + wbase;
    char* lb = (char*)lds_b + buf * 8192 + wbase;
    gload_lds16(ar0 + k0, la);
    gload_lds16(ar1 + k0, la + 4096);
    gload_lds16(br0 + k0, lb);
    gload_lds16(br1 + k0, lb + 4096);
  };

  stage(0, 0);
  __syncthreads();
  int cur = 0;
  for (int kt = 0; kt < nk; ++kt) {
    if (kt + 1 < nk) stage(kt + 1, cur ^ 1);
    const char* la = (const char*)lds_a + cur * 8192;
    const char* lb = (const char*)lds_b + cur * 8192;
    bf16x8 af[2], bfv[5];
    #pragma unroll
    for (int m = 0; m < 2; ++m) {
      int rw = wid * 32 + m * 16 + (lane & 15);
      int pp = (lane >> 4) ^ ((rw >> 1) & 3);
      af[m] = *(const bf16x8*)(la + rw * 64 + (pp << 4));
    }
    #pragma unroll
    for (int n = 0; n < 5; ++n) {
      int nn = n * 16 + (lane & 15);
      int pp = (lane >> 4) ^ ((nn >> 1) & 3);
      bfv[n] = *(const bf16x8*)(lb + nn * 64 + (pp << 4));
    }
    #pragma unroll
    for (int m = 0; m < 2; ++m)
      #pragma unroll
      for (int n = 0; n < 5; ++n)
        acc[m][n] = __builtin_amdgcn_mfma_f32_16x16x32_bf16(af[m], bfv[n], acc[m][n], 0, 0, 0);
    __syncthreads();
    cur ^= 1;
  }

  #pragma unroll
  for (int fm = 0; fm < 2; ++fm)
    #pragma unroll
    for (int fn = 0; fn < 5; ++fn)
      #pragma unroll
      for (int rr = 0; rr < 4; ++rr) {
        int rw = m0 + wid * 32 + fm * 16 + (lane >> 4) * 4 + rr;
        int col = fn * 16 + (lane & 15);
        lp[(long)rw * NH + col] = f2bf(acc[fm][fn][rr]);
      }
}

// ---------------- heads GEMM: 4 chunks (past t0..t2, cur) -> slots 0..3
__global__ __launch_bounds__(256)
void gemm_heads_kernel(const short* __restrict__ pastR, const short* __restrict__ curR,
                       const short* __restrict__ headwT, short* __restrict__ linpart, int G)
{
  int kc = blockIdx.x;        // 0..3
  int m0 = blockIdx.y * 128;
  int g  = blockIdx.z;
  const short* abase;
  const short* hb;
  if (kc == 3) { abase = curR + (long)g * AP * DD; hb = headwT + 4 * DD; }
  else         { abase = pastR + (long)(g * 3 + kc) * AP * DD; hb = headwT + kc * DD; }
  __shared__ short lds_a[2 * 128 * 32];
  __shared__ short lds_b[2 * 128 * 32];
  short* lp = linpart + (long)(kc * G + g) * AP * NH;
  gemm_n80_body(abase, DD, m0, hb, KH, lp, DD / 32, lds_a, lds_b);
}

// ---------------- skinny GEMM: linpart slots 4..7 = K-partials of M @ curW3T^T
__global__ __launch_bounds__(256)
void gemm_skinny_kernel(const short* __restrict__ scores, const short* __restrict__ curW3T,
                        short* __restrict__ linpart, int G)
{
  int kc = blockIdx.x;        // 0..3, K-chunk of 704 over AP
  int m0 = blockIdx.y * 128;
  int g  = blockIdx.z;
  const short* abase = scores + (long)g * AP * AP + (long)kc * 704;
  const short* hb    = curW3T + (long)g * NHP * AP + (long)kc * 704;
  __shared__ short lds_a[2 * 128 * 32];
  __shared__ short lds_b[2 * 128 * 32];
  short* lp = linpart + (long)((4 + kc) * G + g) * AP * NH;
  gemm_n80_body(abase, AP, m0, hb, AP, lp, 704 / 32, lds_a, lds_b);
}

// ---------------- assemble G batches: out[g][a][c], summing 8 bf16 K-partials
__global__ void assemble_kernel(const short* __restrict__ linpart, const float* __restrict__ anchors,
                                const float* __restrict__ cls_b, const float* __restrict__ reg_b,
                                float* __restrict__ out_b0, int G)
{
  long idx = (long)blockIdx.x * 256 + threadIdx.x;
  const long per_g = (long)AREAL * 77;
  if (idx >= per_g * G) return;
  int g = (int)(idx / per_g);
  long rem = idx - (long)g * per_g;
  int c = (int)(rem % 77);
  int a = (int)(rem / 77);
  float v;
  if (c == 2) {
    v = anchors[(long)a * 77 + 2];
  } else {
    int col = (c < 2) ? c : (2 + (c - 3));
    float s = 0.f;
    #pragma unroll
    for (int sl = 0; sl < 8; ++sl)
      s += bf2f(linpart[((long)(sl * G + g) * AP + a) * NH + col]);
    v = (c < 2) ? (s + cls_b[c]) : (anchors[(long)a * 77 + c] + s + reg_b[c - 3]);
  }
  out_b0[idx] = v;
}

extern "C" void kernel_launch(void* const* d_in, const int* in_sizes, int n_in,
                              void* d_out, int out_size, void* d_ws, size_t ws_size,
                              hipStream_t stream)
{
  (void)in_sizes; (void)n_in; (void)out_size;
  const float* x        = (const float*)d_in[0];
  const float* conv1_w  = (const float*)d_in[1];
  const float* conv1_b  = (const float*)d_in[2];
  const float* att_w    = (const float*)d_in[3];
  const float* att_b    = (const float*)d_in[4];
  const float* cls_w    = (const float*)d_in[5];
  const float* cls_b    = (const float*)d_in[6];
  const float* reg_w    = (const float*)d_in[7];
  const float* reg_b    = (const float*)d_in[8];
  const float* anchors  = (const float*)d_in[9];
  const int*   cut_xs   = (const int*)d_in[10];
  const int*   invalid  = (const int*)d_in[11];
  float* out = (float*)d_out;

  auto align256 = [](size_t v) { return (v + 255) & ~(size_t)255; };
  const size_t sz_feats  = align256((size_t)BB * TT * PPAD * 128 * 2);
  const size_t sz_wbf    = align256((size_t)128 * CIN * 2);
  const size_t sz_attwT  = align256((size_t)AP * DD * 2);
  const size_t sz_headwT = align256((size_t)NHP * KH * 2);
  const size_t sz_gidx   = align256((size_t)AREAL * HH * 4);
  const size_t misc = sz_feats + sz_wbf + sz_attwT + sz_headwT + sz_gidx;
  auto per_g = [&](int G) {
    return align256((size_t)G * AP * DD * 2)      // curR
         + align256((size_t)G * AP * AP * 2)      // scores (hosts xT, pastR)
         + align256((size_t)G * NHP * AP * 2)     // curW3T
         + align256((size_t)8 * G * AP * NH * 2); // linpart (8 slots)
  };
  int G = 1;
  for (int cand : {8, 4, 2}) {
    if (misc + per_g(cand) + (1u << 20) <= ws_size) { G = cand; break; }
  }

  char* p = (char*)d_ws;
  short* feats_po = (short*)p; p += sz_feats;
  short* w_bf16   = (short*)p; p += sz_wbf;
  short* attwT    = (short*)p; p += sz_attwT;
  short* headwT   = (short*)p; p += sz_headwT;
  int*   gidx     = (int*)p;   p += sz_gidx;
  short* curR     = (short*)p; p += align256((size_t)G * AP * DD * 2);
  short* scores   = (short*)p; p += align256((size_t)G * AP * AP * 2);
  short* curW3T   = (short*)p; p += align256((size_t)G * NHP * AP * 2);
  short* linpart  = (short*)p; p += align256((size_t)8 * G * AP * NH * 2);
  short* xT       = scores;               // 8.39 MB <= G*15.86 MB
  short* pastR    = scores;               // G*11.9 MB <= G*15.86 MB (written after skinny reads)

  transpose_x_kernel<<<dim3(BB * TT, CIN / 32), 256, 0, stream>>>(x, xT);
  prep_wbf_kernel<<<(128 * CIN + 255) / 256, 256, 0, stream>>>(conv1_w, w_bf16);
  prep_attw_kernel<<<dim3(AP / 32, DD / 32), 256, 0, stream>>>(att_w, attwT);
  prep_headw_kernel<<<(NHP * KH + 255) / 256, 256, 0, stream>>>(cls_w, reg_w, headwT);
  prep_gidx_kernel<<<(AREAL * HH + 255) / 256, 256, 0, stream>>>(cut_xs, invalid, gidx);

  // conv as GEMM: feats_po[bt*256+p][o]
  gemm_nt_kernel<1><<<dim3(1, BB * TT * PPAD / 128, 1), 256, 0, stream>>>(
      xT, 0, CIN, w_bf16, 0, CIN, feats_po, 0, 128, CIN, conv1_b, CAF);

  for (int b0 = 0; b0 < BB; b0 += G) {
    const short* fpo = feats_po + (long)b0 * TT * PPAD * 128;

    gather_cur_kernel<<<dim3(AP * 88 / 256, G), 256, 0, stream>>>(fpo, gidx, curR);

    // scores = cur @ attwT^T + att_b  — flattened GEMM: M = G*AP, 256² deep
    gemm256_nt_kernel<<<dim3(AP / 256, G * AP / 256, 1), 512, 0, stream>>>(
        curR, 0, DD, attwT, 0, DD, scores, 0, AP, DD, att_b, NATT);

    softmax_shift_kernel<<<dim3(AREAL, G), 256, 0, stream>>>(scores);

    // curW3T[g][n][j] = sum_d headwT[n][2112+d] * curR[g][j][d]
    gemm_nt_kernel<0><<<dim3(AP / 128, 1, G), 256, 0, stream>>>(
        headwT + 3 * DD, 0, KH, curR, (long long)AP * DD, DD,
        curW3T, (long long)NHP * AP, AP, DD, nullptr, 0);

    // linpart slots 4..7: M @ curW3T^T, K split 4x704 (reads scores before pastR overlay)
    gemm_skinny_kernel<<<dim3(4, AP / 128, G), 256, 0, stream>>>(scores, curW3T, linpart, G);

    gather_past_kernel<<<dim3(AP * 88 / 256, 3 * G), 256, 0, stream>>>(fpo, gidx, pastR);

    // linpart slots 0..3: past t0..t2 + cur chunks
    gemm_heads_kernel<<<dim3(4, AP / 128, G), 256, 0, stream>>>(pastR, curR, headwT, linpart, G);

    assemble_kernel<<<(int)(((long)G * AREAL * 77 + 255) / 256), 256, 0, stream>>>(
        linpart, anchors, cls_b, reg_b, out + (long)b0 * AREAL * 77, G);
  }
}

// Round 13
// 358.870 us; speedup vs baseline: 1.2982x; 1.0578x over previous
//
#include <hip/hip_runtime.h>

#define BB 8
#define TT 4
#define CIN 512
#define CAF 64
#define HH 11
#define WW 20
#define PP 220           // H*W positions
#define PPAD 256
#define AREAL 2784
#define AP 2816          // padded anchors
#define DD 704           // C_AF*H
#define NH 80            // padded head cols (2 cls + 74 reg)
#define NHP 128          // padded head rows for B-staging
#define NATT 2783        // A-1

typedef __attribute__((ext_vector_type(8))) short bf16x8;
typedef __attribute__((ext_vector_type(4))) float floatx4;

__device__ __forceinline__ short f2bf(float f) {
  unsigned u = __float_as_uint(f);
  u += 0x7fffu + ((u >> 16) & 1u);
  return (short)(u >> 16);
}
__device__ __forceinline__ float bf2f(short s) {
  return __uint_as_float(((unsigned)(unsigned short)s) << 16);
}

__device__ __forceinline__ void gload_lds16(const void* g, void* l) {
  __builtin_amdgcn_global_load_lds(
      (const __attribute__((address_space(1))) void*)g,
      (__attribute__((address_space(3))) void*)l, 16, 0, 0);
}

// ---------------- xT[bt][p(256)][c(512)] = bf16(x[bt][c][p]), p>=220 -> 0
__global__ __launch_bounds__(256)
void transpose_x_kernel(const float* __restrict__ x, short* __restrict__ xT)
{
  int bt = blockIdx.x;        // 0..31
  int c0 = blockIdx.y * 32;   // 0..480
  __shared__ float xs[32 * PP];
  int tid = threadIdx.x;
  const float* xp = x + ((long)bt * CIN + c0) * PP;
  for (int i = tid; i < 32 * PP; i += 256) xs[i] = xp[i];
  __syncthreads();
  short* op = xT + (long)bt * PPAD * CIN + c0;
  for (int j = tid; j < PPAD * 32; j += 256) {
    int p = j >> 5, cc = j & 31;
    short v = 0;
    if (p < PP) v = f2bf(xs[cc * PP + p]);
    op[(long)p * CIN + cc] = v;
  }
}

// ---------------- w_bf16[n(128)][c(512)]: n<64 -> conv1_w[n][c], else 0
__global__ void prep_wbf_kernel(const float* __restrict__ w, short* __restrict__ wb)
{
  int idx = blockIdx.x * 256 + threadIdx.x;
  if (idx >= 128 * CIN) return;
  int n = idx >> 9, c = idx & 511;
  wb[idx] = (n < CAF) ? f2bf(w[(long)n * CIN + c]) : (short)0;
}

// ---------------- gidx[a][hh] = invalid ? -1 : (hh*20+xw)*128
__global__ void prep_gidx_kernel(const int* __restrict__ cut_xs, const int* __restrict__ invalid,
                                 int* __restrict__ gidx)
{
  int idx = blockIdx.x * 256 + threadIdx.x;
  if (idx >= AREAL * HH) return;
  int hh = idx % HH;
  gidx[idx] = invalid[idx] ? -1 : (hh * WW + cut_xs[idx]) * 128;
}

// ---------------- gather cur (t=3), d-major vectorized
__global__ __launch_bounds__(256)
void gather_cur_kernel(const short* __restrict__ fpo_base, const int* __restrict__ gidx,
                       short* __restrict__ curR)
{
  int g = blockIdx.y;
  int idx = blockIdx.x * 256 + threadIdx.x;   // over AP*88
  int a = idx / 88;
  int ch = idx - a * 88;
  int d0 = ch * 8;
  bf16x8 v = {};
  if (a < AREAL) {
    const short* fp = fpo_base + ((long)g * TT + 3) * PPAD * 128;
    #pragma unroll
    for (int e = 0; e < 8; ++e) {
      int d = d0 + e;
      int o = d / 11;
      int hh = d - o * 11;
      int gi = gidx[a * 11 + hh];
      v[e] = (gi < 0) ? (short)0 : fp[gi + o];
    }
  }
  *(bf16x8*)(curR + ((long)g * AP + a) * DD + d0) = v;
}

// ---------------- attw_T[n][d] = att_w[d][n] bf16 (pad -> 0)
__global__ __launch_bounds__(256)
void prep_attw_kernel(const float* __restrict__ att_w, short* __restrict__ attwT)
{
  int n0 = blockIdx.x * 32;
  int d0 = blockIdx.y * 32;
  __shared__ float tile[32][33];
  int tid = threadIdx.x;
  for (int i = tid; i < 1024; i += 256) {
    int r = i >> 5, c = i & 31;
    int d = d0 + r, n = n0 + c;
    tile[r][c] = (d < DD && n < NATT) ? att_w[(long)d * NATT + n] : 0.f;
  }
  __syncthreads();
  for (int i = tid; i < 1024; i += 256) {
    int r = i >> 5, c = i & 31;
    attwT[(long)(n0 + r) * DD + d0 + c] = f2bf(tile[c][r]);
  }
}

// ---------------- prep_tables: T[b][t5][hh][x][n] = sum_o feats[b][tsel][(hh*20+x)*128+o]
//                  * W[n][t5*DD + o*11 + hh],  tsel = min(t5,3); W from fp32 cls_w/reg_w
__global__ __launch_bounds__(256)
void prep_tables_kernel(const short* __restrict__ feats_po,
                        const float* __restrict__ cls_w, const float* __restrict__ reg_w,
                        float* __restrict__ T)
{
  int bid = blockIdx.x;         // b*55 + t5*11 + hh
  int b = bid / 55; int r = bid - b * 55; int t5 = r / 11; int hh = r - t5 * 11;
  int tsel = t5 < 3 ? t5 : 3;
  const short* fp = feats_po + ((long)(b * TT + tsel) * PPAD + hh * WW) * 128;
  __shared__ float fs[20 * 64];
  __shared__ float wsl[80 * 65];
  int tid = threadIdx.x;
  for (int i = tid; i < 1280; i += 256) {
    int x = i >> 6, o = i & 63;
    fs[i] = bf2f(fp[x * 128 + o]);
  }
  for (int i = tid; i < 5120; i += 256) {
    int n = i >> 6, o = i & 63;
    int k = t5 * DD + o * 11 + hh;
    float v = 0.f;
    if (n < 2) v = cls_w[(long)k * 2 + n];
    else if (n < 76) v = reg_w[(long)k * 74 + (n - 2)];
    wsl[n * 65 + o] = v;
  }
  __syncthreads();
  float* Tb = T + (long)bid * 1600;
  for (int j = tid; j < 1600; j += 256) {
    int x = j / 80, n = j - (j / 80) * 80;
    float s = 0.f;
    #pragma unroll
    for (int o = 0; o < 64; ++o) s += fs[x * 64 + o] * wsl[n * 65 + o];
    Tb[x * 80 + n] = s;
  }
}

// ---------------- tgather_heads: linpart slot0[g][a][n] = sum_{t5 in {0,1,2,4}, hh}
//                  mask * T[b][t5][hh][x_{a,hh}][n]   (combined past+cur head contribution)
__global__ __launch_bounds__(256)
void tgather_heads_kernel(const float* __restrict__ T, const int* __restrict__ cut_xs,
                          const int* __restrict__ invalid, short* __restrict__ linpart,
                          int b0, int G)
{
  int g = blockIdx.y; int b = b0 + g;
  int idx = blockIdx.x * 256 + threadIdx.x;
  if (idx >= AREAL * 80) return;
  int a = idx / 80, n = idx - (idx / 80) * 80;
  const float* Tb = T + (long)b * 55 * 1600;
  float s = 0.f;
  #pragma unroll
  for (int hh = 0; hh < 11; ++hh) {
    int x = cut_xs[a * 11 + hh];
    if (!invalid[a * 11 + hh]) {
      int base = x * 80 + n;
      s += Tb[(0 * 11 + hh) * 1600 + base];
      s += Tb[(1 * 11 + hh) * 1600 + base];
      s += Tb[(2 * 11 + hh) * 1600 + base];
      s += Tb[(4 * 11 + hh) * 1600 + base];
    }
  }
  linpart[((long)(0 * G + g) * AP + a) * NH + n] = f2bf(s);
}

// ---------------- tgather_w3: curW3T[g][n][j] = sum_hh mask * T[b][3][hh][x_{j,hh}][n]
__global__ __launch_bounds__(256)
void tgather_w3_kernel(const float* __restrict__ T, const int* __restrict__ cut_xs,
                       const int* __restrict__ invalid, short* __restrict__ curW3T,
                       int b0, int G)
{
  int g = blockIdx.y; int b = b0 + g;
  int idx = blockIdx.x * 256 + threadIdx.x;   // over NHP*AP
  if (idx >= NHP * AP) return;
  int n = idx / AP, j = idx - (idx / AP) * AP;
  float s = 0.f;
  if (n < 80 && j < AREAL) {
    const float* Tb = T + ((long)b * 55 + 3 * 11) * 1600;
    #pragma unroll
    for (int hh = 0; hh < 11; ++hh) {
      int x = cut_xs[j * 11 + hh];
      if (!invalid[j * 11 + hh]) s += Tb[hh * 1600 + x * 80 + n];
    }
  }
  curW3T[(long)g * NHP * AP + idx] = f2bf(s);
}

// ================= 256x256 deep-pipelined NT GEMM (round-8 schedule) =================
__global__ __launch_bounds__(512, 2)
void gemm256_nt_kernel(const short* __restrict__ A, long long aBatch, int lda,
                       const short* __restrict__ Bt, long long bBatch, int ldb,
                       short* __restrict__ C, long long cBatch, int ldc,
                       int K, const float* __restrict__ bias, int biasN)
{
  int gx = gridDim.x, gy = gridDim.y;
  int nwg = gx * gy * gridDim.z;
  int o = blockIdx.x + gx * (blockIdx.y + gy * blockIdx.z);
  int xcd = o & 7, pos = o >> 3;
  int q = nwg >> 3, r = nwg & 7;
  int nid = (xcd < r ? xcd * (q + 1) : r * (q + 1) + (xcd - r) * q) + pos;
  int bx = nid % gx; int tq = nid / gx; int by = tq % gy; int bz = tq / gy;

  A  += (long long)bz * aBatch;
  Bt += (long long)bz * bBatch;
  C  += (long long)bz * cBatch;
  int M0 = by * 256, N0 = bx * 256;

  __shared__ short lds_a[2 * 256 * 64];
  __shared__ short lds_b[2 * 256 * 64];

  int tid = threadIdx.x, lane = tid & 63, w = tid >> 6;
  int wr = w >> 2, wc = w & 3;

  floatx4 acc[8][4];
  #pragma unroll
  for (int m = 0; m < 8; ++m)
    #pragma unroll
    for (int n = 0; n < 4; ++n) acc[m][n] = floatx4{0.f, 0.f, 0.f, 0.f};

  int rl = tid >> 3, sl = tid & 7;
  int ssl = sl ^ (rl & 7);
  const short* aS = A  + (long)(M0 + rl) * lda + ssl * 8;
  const short* bS = Bt + (long)(N0 + rl) * ldb + ssl * 8;
  char* la0 = (char*)lds_a;
  char* lb0 = (char*)lds_b;
  int wub = (tid & ~63) * 16;

  auto stage = [&](int kt, int buf) {
    long ko = (long)kt * 64;
    #pragma unroll
    for (int c = 0; c < 4; ++c) {
      gload_lds16(aS + (long)c * 64 * lda + ko, la0 + buf * 32768 + c * 8192 + wub);
      gload_lds16(bS + (long)c * 64 * ldb + ko, lb0 + buf * 32768 + c * 8192 + wub);
    }
  };
  auto rdA = [&](int buf, int mf, int kk) -> bf16x8 {
    int row = wr * 128 + mf * 16 + (lane & 15);
    int phys = (kk * 4 + (lane >> 4)) ^ (lane & 7);
    return *(const bf16x8*)(la0 + buf * 32768 + row * 128 + phys * 16);
  };
  auto rdB = [&](int buf, int nf, int kk) -> bf16x8 {
    int row = wc * 64 + nf * 16 + (lane & 15);
    int phys = (kk * 4 + (lane >> 4)) ^ (lane & 7);
    return *(const bf16x8*)(lb0 + buf * 32768 + row * 128 + phys * 16);
  };

  int nt = K >> 6;
  stage(0, 0);
  stage(1, 1);
  asm volatile("s_waitcnt vmcnt(8)" ::: "memory");
  __builtin_amdgcn_sched_barrier(0);
  __builtin_amdgcn_s_barrier();
  __builtin_amdgcn_sched_barrier(0);

  for (int t = 0; t < nt; ++t) {
    int buf = t & 1;
    bf16x8 A0[2][4], A1[2][4], B0[2][2], B1[2][2];
    #pragma unroll
    for (int kk = 0; kk < 2; ++kk) {
      #pragma unroll
      for (int i = 0; i < 4; ++i) A0[kk][i] = rdA(buf, i, kk);
      #pragma unroll
      for (int j = 0; j < 2; ++j) B0[kk][j] = rdB(buf, j, kk);
    }
    __builtin_amdgcn_s_setprio(1);
    #pragma unroll
    for (int kk = 0; kk < 2; ++kk)
      #pragma unroll
      for (int i = 0; i < 4; ++i)
        #pragma unroll
        for (int j = 0; j < 2; ++j)
          acc[i][j] = __builtin_amdgcn_mfma_f32_16x16x32_bf16(A0[kk][i], B0[kk][j], acc[i][j], 0, 0, 0);
    __builtin_amdgcn_s_setprio(0);
    #pragma unroll
    for (int kk = 0; kk < 2; ++kk)
      #pragma unroll
      for (int j = 0; j < 2; ++j) B1[kk][j] = rdB(buf, 2 + j, kk);
    __builtin_amdgcn_s_setprio(1);
    #pragma unroll
    for (int kk = 0; kk < 2; ++kk)
      #pragma unroll
      for (int i = 0; i < 4; ++i)
        #pragma unroll
        for (int j = 0; j < 2; ++j)
          acc[i][2 + j] = __builtin_amdgcn_mfma_f32_16x16x32_bf16(A0[kk][i], B1[kk][j], acc[i][2 + j], 0, 0, 0);
    __builtin_amdgcn_s_setprio(0);
    #pragma unroll
    for (int kk = 0; kk < 2; ++kk)
      #pragma unroll
      for (int i = 0; i < 4; ++i) A1[kk][i] = rdA(buf, 4 + i, kk);
    __builtin_amdgcn_s_setprio(1);
    #pragma unroll
    for (int kk = 0; kk < 2; ++kk)
      #pragma unroll
      for (int i = 0; i < 4; ++i)
        #pragma unroll
        for (int j = 0; j < 2; ++j)
          acc[4 + i][2 + j] = __builtin_amdgcn_mfma_f32_16x16x32_bf16(A1[kk][i], B1[kk][j], acc[4 + i][2 + j], 0, 0, 0);
    __builtin_amdgcn_s_setprio(0);
    __builtin_amdgcn_sched_barrier(0);
    __builtin_amdgcn_s_barrier();
    __builtin_amdgcn_sched_barrier(0);
    if (t + 2 < nt) stage(t + 2, buf);
    __builtin_amdgcn_s_setprio(1);
    #pragma unroll
    for (int kk = 0; kk < 2; ++kk)
      #pragma unroll
      for (int i = 0; i < 4; ++i)
        #pragma unroll
        for (int j = 0; j < 2; ++j)
          acc[4 + i][j] = __builtin_amdgcn_mfma_f32_16x16x32_bf16(A1[kk][i], B0[kk][j], acc[4 + i][j], 0, 0, 0);
    __builtin_amdgcn_s_setprio(0);
    if (t + 2 < nt) {
      asm volatile("s_waitcnt vmcnt(8)" ::: "memory");
    } else {
      asm volatile("s_waitcnt vmcnt(0)" ::: "memory");
    }
    __builtin_amdgcn_sched_barrier(0);
    __builtin_amdgcn_s_barrier();
    __builtin_amdgcn_sched_barrier(0);
  }

  #pragma unroll
  for (int mf = 0; mf < 8; ++mf) {
    #pragma unroll
    for (int nf = 0; nf < 4; ++nf) {
      int col = N0 + wc * 64 + nf * 16 + (lane & 15);
      float bv = 0.f;
      if (bias) bv = (col < biasN) ? bias[col] : 0.f;
      #pragma unroll
      for (int rr = 0; rr < 4; ++rr) {
        int rowc = M0 + wr * 128 + mf * 16 + (lane >> 4) * 4 + rr;
        C[(long)rowc * ldc + col] = f2bf(acc[mf][nf][rr] + bv);
      }
    }
  }
}

// ---------------- batched NT GEMM: 128x128 tile, 2-phase dbuf (conv)
template<int WITH_BIAS>
__global__ __launch_bounds__(256)
void gemm_nt_kernel(const short* __restrict__ A, long long aBatch, int lda,
                    const short* __restrict__ Bt, long long bBatch, int ldb,
                    short* __restrict__ C, long long cBatch, int ldc,
                    int K, const float* __restrict__ bias, int biasN)
{
  int gx = gridDim.x, gy = gridDim.y;
  int nwg = gx * gy * gridDim.z;
  int o = blockIdx.x + gx * (blockIdx.y + gy * blockIdx.z);
  int xcd = o & 7, pos = o >> 3;
  int q = nwg >> 3, r = nwg & 7;
  int nid = (xcd < r ? xcd * (q + 1) : r * (q + 1) + (xcd - r) * q) + pos;
  int bx = nid % gx; int t = nid / gx; int by = t % gy; int bz = t / gy;

  A  += (long long)bz * aBatch;
  Bt += (long long)bz * bBatch;
  C  += (long long)bz * cBatch;
  int m0 = by * 128;
  int n0 = bx * 128;

  __shared__ short lds_a[2 * 128 * 32];
  __shared__ short lds_b[2 * 128 * 32];

  int tid = threadIdx.x;
  int lane = tid & 63;
  int wid = tid >> 6;
  int wr = wid >> 1, wc = wid & 1;
  int row = tid >> 2;
  int slot = tid & 3;

  floatx4 acc[4][4];
  #pragma unroll
  for (int m = 0; m < 4; ++m)
    #pragma unroll
    for (int n = 0; n < 4; ++n) acc[m][n] = floatx4{0.f, 0.f, 0.f, 0.f};

  int wbase = (tid & ~63) * 16;
  int ks0 = slot ^ ((row >> 1) & 3);
  int ks1 = slot ^ (((row + 64) >> 1) & 3);
  const short* ar0 = A  + (long)(m0 + row) * lda + ks0 * 8;
  const short* ar1 = A  + (long)(m0 + row + 64) * lda + ks1 * 8;
  const short* br0 = Bt + (long)(n0 + row) * ldb + ks0 * 8;
  const short* br1 = Bt + (long)(n0 + row + 64) * ldb + ks1 * 8;

  auto stage = [&](int kt, int buf) {
    int k0 = kt * 32;
    char* la = (char*)lds_a + buf * 8192 + wbase;
    char* lb = (char*)lds_b + buf * 8192 + wbase;
    gload_lds16(ar0 + k0, la);
    gload_lds16(ar1 + k0, la + 4096);
    gload_lds16(br0 + k0, lb);
    gload_lds16(br1 + k0, lb + 4096);
  };

  int nk = K >> 5;
  stage(0, 0);
  __syncthreads();
  int cur = 0;
  for (int kt = 0; kt < nk; ++kt) {
    if (kt + 1 < nk) stage(kt + 1, cur ^ 1);
    const char* ba = (const char*)lds_a + cur * 8192;
    const char* bb = (const char*)lds_b + cur * 8192;
    bf16x8 af[4], bfv[4];
    #pragma unroll
    for (int m = 0; m < 4; ++m) {
      int rw = wr * 64 + m * 16 + (lane & 15);
      int pp = (lane >> 4) ^ ((rw >> 1) & 3);
      af[m] = *(const bf16x8*)(ba + rw * 64 + (pp << 4));
    }
    #pragma unroll
    for (int n = 0; n < 4; ++n) {
      int rw = wc * 64 + n * 16 + (lane & 15);
      int pp = (lane >> 4) ^ ((rw >> 1) & 3);
      bfv[n] = *(const bf16x8*)(bb + rw * 64 + (pp << 4));
    }
    #pragma unroll
    for (int m = 0; m < 4; ++m)
      #pragma unroll
      for (int n = 0; n < 4; ++n)
        acc[m][n] = __builtin_amdgcn_mfma_f32_16x16x32_bf16(af[m], bfv[n], acc[m][n], 0, 0, 0);
    __syncthreads();
    cur ^= 1;
  }

  #pragma unroll
  for (int m = 0; m < 4; ++m) {
    #pragma unroll
    for (int n = 0; n < 4; ++n) {
      int col = n0 + wc * 64 + n * 16 + (lane & 15);
      float bv = 0.f;
      if (WITH_BIAS) bv = (col < biasN) ? bias[col] : 0.f;
      #pragma unroll
      for (int rr = 0; rr < 4; ++rr) {
        int rowc = m0 + wr * 64 + m * 16 + (lane >> 4) * 4 + rr;
        C[(long)rowc * ldc + col] = f2bf(acc[m][n][rr] + bv);
      }
    }
  }
}

// ---------------- per-row softmax + shifted M-row write in place (vectorized)
__global__ __launch_bounds__(256)
void softmax_shift_kernel(short* __restrict__ scores)
{
  int g = blockIdx.y;
  int i = blockIdx.x;   // 0..2783
  short* row = scores + (long)g * AP * AP + (long)i * AP;
  __shared__ float vals[NATT];
  __shared__ float red[4];
  int tid = threadIdx.x;

  float lmax = -1e30f;
  for (int jc = tid; jc < 348; jc += 256) {
    bf16x8 v8 = *(const bf16x8*)(row + jc * 8);
    #pragma unroll
    for (int e = 0; e < 8; ++e) {
      int j = jc * 8 + e;
      float f = bf2f(v8[e]);
      if (j < NATT) { vals[j] = f; lmax = fmaxf(lmax, f); }
    }
  }
  #pragma unroll
  for (int off = 32; off; off >>= 1) lmax = fmaxf(lmax, __shfl_down(lmax, off, 64));
  if ((tid & 63) == 0) red[tid >> 6] = lmax;
  __syncthreads();
  float mx = fmaxf(fmaxf(red[0], red[1]), fmaxf(red[2], red[3]));
  __syncthreads();

  float lsum = 0.f;
  for (int j = tid; j < NATT; j += 256) {
    float e = __expf(vals[j] - mx);
    vals[j] = e;
    lsum += e;
  }
  #pragma unroll
  for (int off = 32; off; off >>= 1) lsum += __shfl_down(lsum, off, 64);
  if ((tid & 63) == 0) red[tid >> 6] = lsum;
  __syncthreads();
  float inv = 1.f / (red[0] + red[1] + red[2] + red[3]);
  __syncthreads();

  for (int jc = tid; jc < 352; jc += 256) {
    bf16x8 o8;
    #pragma unroll
    for (int e = 0; e < 8; ++e) {
      int j = jc * 8 + e;
      float v;
      if (j < i)            v = vals[j] * inv;
      else if (j == i)      v = 0.f;
      else if (j < AREAL)   v = vals[j - 1] * inv;
      else                  v = 0.f;
      o8[e] = f2bf(v);
    }
    *(bf16x8*)(row + jc * 8) = o8;
  }
}

// ---------------- N=80 GEMM core: gload_lds staging, 2-phase dbuf
__device__ __forceinline__
void gemm_n80_body(const short* __restrict__ abase, int ald, int m0,
                   const short* __restrict__ hb, int ldbh,
                   short* __restrict__ lp, int nk,
                   short* lds_a, short* lds_b)
{
  int tid = threadIdx.x, lane = tid & 63, wid = tid >> 6;

  floatx4 acc[2][5];
  #pragma unroll
  for (int m = 0; m < 2; ++m)
    #pragma unroll
    for (int n = 0; n < 5; ++n) acc[m][n] = floatx4{0.f, 0.f, 0.f, 0.f};

  int wbase = (tid & ~63) * 16;
  int row = tid >> 2;
  int slot = tid & 3;
  int ks0 = slot ^ ((row >> 1) & 3);
  int ks1 = slot ^ (((row + 64) >> 1) & 3);
  const short* ar0 = abase + (long)(m0 + row) * ald + ks0 * 8;
  const short* ar1 = abase + (long)(m0 + row + 64) * ald + ks1 * 8;
  const short* br0 = hb + (long)row * ldbh + ks0 * 8;
  const short* br1 = hb + (long)(row + 64) * ldbh + ks1 * 8;

  auto stage = [&](int kt, int buf) {
    int k0 = kt * 32;
    char* la = (char*)lds_a + buf * 8192 + wbase;
    char* lb = (char*)lds_b + buf * 8192 + wbase;
    gload_lds16(ar0 + k0, la);
    gload_lds16(ar1 + k0, la + 4096);
    gload_lds16(br0 + k0, lb);
    gload_lds16(br1 + k0, lb + 4096);
  };

  stage(0, 0);
  __syncthreads();
  int cur = 0;
  for (int kt = 0; kt < nk; ++kt) {
    if (kt + 1 < nk) stage(kt + 1, cur ^ 1);
    const char* la = (const char*)lds_a + cur * 8192;
    const char* lb = (const char*)lds_b + cur * 8192;
    bf16x8 af[2], bfv[5];
    #pragma unroll
    for (int m = 0; m < 2; ++m) {
      int rw = wid * 32 + m * 16 + (lane & 15);
      int pp = (lane >> 4) ^ ((rw >> 1) & 3);
      af[m] = *(const bf16x8*)(la + rw * 64 + (pp << 4));
    }
    #pragma unroll
    for (int n = 0; n < 5; ++n) {
      int nn = n * 16 + (lane & 15);
      int pp = (lane >> 4) ^ ((nn >> 1) & 3);
      bfv[n] = *(const bf16x8*)(lb + nn * 64 + (pp << 4));
    }
    #pragma unroll
    for (int m = 0; m < 2; ++m)
      #pragma unroll
      for (int n = 0; n < 5; ++n)
        acc[m][n] = __builtin_amdgcn_mfma_f32_16x16x32_bf16(af[m], bfv[n], acc[m][n], 0, 0, 0);
    __syncthreads();
    cur ^= 1;
  }

  #pragma unroll
  for (int fm = 0; fm < 2; ++fm)
    #pragma unroll
    for (int fn = 0; fn < 5; ++fn)
      #pragma unroll
      for (int rr = 0; rr < 4; ++rr) {
        int rw = m0 + wid * 32 + fm * 16 + (lane >> 4) * 4 + rr;
        int col = fn * 16 + (lane & 15);
        lp[(long)rw * NH + col] = f2bf(acc[fm][fn][rr]);
      }
}

// ---------------- skinny GEMM: linpart slots 1..4 = K-partials of M @ curW3T^T
__global__ __launch_bounds__(256)
void gemm_skinny_kernel(const short* __restrict__ scores, const short* __restrict__ curW3T,
                        short* __restrict__ linpart, int G)
{
  int kc = blockIdx.x;        // 0..3, K-chunk of 704 over AP
  int m0 = blockIdx.y * 128;
  int g  = blockIdx.z;
  const short* abase = scores + (long)g * AP * AP + (long)kc * 704;
  const short* hb    = curW3T + (long)g * NHP * AP + (long)kc * 704;
  __shared__ short lds_a[2 * 128 * 32];
  __shared__ short lds_b[2 * 128 * 32];
  short* lp = linpart + (long)((1 + kc) * G + g) * AP * NH;
  gemm_n80_body(abase, AP, m0, hb, AP, lp, 704 / 32, lds_a, lds_b);
}

// ---------------- assemble G batches: out[g][a][c], summing 5 bf16 K-partials
__global__ void assemble_kernel(const short* __restrict__ linpart, const float* __restrict__ anchors,
                                const float* __restrict__ cls_b, const float* __restrict__ reg_b,
                                float* __restrict__ out_b0, int G)
{
  long idx = (long)blockIdx.x * 256 + threadIdx.x;
  const long per_g = (long)AREAL * 77;
  if (idx >= per_g * G) return;
  int g = (int)(idx / per_g);
  long rem = idx - (long)g * per_g;
  int c = (int)(rem % 77);
  int a = (int)(rem / 77);
  float v;
  if (c == 2) {
    v = anchors[(long)a * 77 + 2];
  } else {
    int col = (c < 2) ? c : (2 + (c - 3));
    float s = 0.f;
    #pragma unroll
    for (int sl = 0; sl < 5; ++sl)
      s += bf2f(linpart[((long)(sl * G + g) * AP + a) * NH + col]);
    v = (c < 2) ? (s + cls_b[c]) : (anchors[(long)a * 77 + c] + s + reg_b[c - 3]);
  }
  out_b0[idx] = v;
}

extern "C" void kernel_launch(void* const* d_in, const int* in_sizes, int n_in,
                              void* d_out, int out_size, void* d_ws, size_t ws_size,
                              hipStream_t stream)
{
  (void)in_sizes; (void)n_in; (void)out_size;
  const float* x        = (const float*)d_in[0];
  const float* conv1_w  = (const float*)d_in[1];
  const float* conv1_b  = (const float*)d_in[2];
  const float* att_w    = (const float*)d_in[3];
  const float* att_b    = (const float*)d_in[4];
  const float* cls_w    = (const float*)d_in[5];
  const float* cls_b    = (const float*)d_in[6];
  const float* reg_w    = (const float*)d_in[7];
  const float* reg_b    = (const float*)d_in[8];
  const float* anchors  = (const float*)d_in[9];
  const int*   cut_xs   = (const int*)d_in[10];
  const int*   invalid  = (const int*)d_in[11];
  float* out = (float*)d_out;

  auto align256 = [](size_t v) { return (v + 255) & ~(size_t)255; };
  const size_t sz_feats  = align256((size_t)BB * TT * PPAD * 128 * 2);
  const size_t sz_wbf    = align256((size_t)128 * CIN * 2);
  const size_t sz_attwT  = align256((size_t)AP * DD * 2);
  const size_t sz_gidx   = align256((size_t)AREAL * HH * 4);
  const size_t sz_T      = align256((size_t)BB * 55 * 1600 * 4);   // 2.8 MB
  const size_t misc = sz_feats + sz_wbf + sz_attwT + sz_gidx + sz_T;
  auto per_g = [&](int G) {
    return align256((size_t)G * AP * DD * 2)      // curR
         + align256((size_t)G * AP * AP * 2)      // scores (hosts xT)
         + align256((size_t)G * NHP * AP * 2)     // curW3T
         + align256((size_t)5 * G * AP * NH * 2); // linpart (5 slots)
  };
  int G = 1;
  for (int cand : {8, 4, 2}) {
    if (misc + per_g(cand) + (1u << 20) <= ws_size) { G = cand; break; }
  }

  char* p = (char*)d_ws;
  short* feats_po = (short*)p; p += sz_feats;
  short* w_bf16   = (short*)p; p += sz_wbf;
  short* attwT    = (short*)p; p += sz_attwT;
  int*   gidx     = (int*)p;   p += sz_gidx;
  float* T        = (float*)p; p += sz_T;
  short* curR     = (short*)p; p += align256((size_t)G * AP * DD * 2);
  short* scores   = (short*)p; p += align256((size_t)G * AP * AP * 2);
  short* curW3T   = (short*)p; p += align256((size_t)G * NHP * AP * 2);
  short* linpart  = (short*)p; p += align256((size_t)5 * G * AP * NH * 2);
  short* xT       = scores;               // 8.39 MB <= G*15.86 MB

  transpose_x_kernel<<<dim3(BB * TT, CIN / 32), 256, 0, stream>>>(x, xT);
  prep_wbf_kernel<<<(128 * CIN + 255) / 256, 256, 0, stream>>>(conv1_w, w_bf16);
  prep_attw_kernel<<<dim3(AP / 32, DD / 32), 256, 0, stream>>>(att_w, attwT);
  prep_gidx_kernel<<<(AREAL * HH + 255) / 256, 256, 0, stream>>>(cut_xs, invalid, gidx);

  // conv as GEMM: feats_po[bt*256+p][o]
  gemm_nt_kernel<1><<<dim3(1, BB * TT * PPAD / 128, 1), 256, 0, stream>>>(
      xT, 0, CIN, w_bf16, 0, CIN, feats_po, 0, 128, CIN, conv1_b, CAF);

  // position-space head tables (all 8 batches)
  prep_tables_kernel<<<BB * 55, 256, 0, stream>>>(feats_po, cls_w, reg_w, T);

  for (int b0 = 0; b0 < BB; b0 += G) {
    const short* fpo = feats_po + (long)b0 * TT * PPAD * 128;

    gather_cur_kernel<<<dim3(AP * 88 / 256, G), 256, 0, stream>>>(fpo, gidx, curR);

    // curW3T via table gather (independent of scores)
    tgather_w3_kernel<<<dim3((NHP * AP + 255) / 256, G), 256, 0, stream>>>(
        T, cut_xs, invalid, curW3T, b0, G);

    // combined heads contribution -> linpart slot 0
    tgather_heads_kernel<<<dim3((AREAL * 80 + 255) / 256, G), 256, 0, stream>>>(
        T, cut_xs, invalid, linpart, b0, G);

    // scores = cur @ attwT^T + att_b  — flattened GEMM: M = G*AP, 256² deep
    gemm256_nt_kernel<<<dim3(AP / 256, G * AP / 256, 1), 512, 0, stream>>>(
        curR, 0, DD, attwT, 0, DD, scores, 0, AP, DD, att_b, NATT);

    softmax_shift_kernel<<<dim3(AREAL, G), 256, 0, stream>>>(scores);

    // linpart slots 1..4: M @ curW3T^T, K split 4x704
    gemm_skinny_kernel<<<dim3(4, AP / 128, G), 256, 0, stream>>>(scores, curW3T, linpart, G);

    assemble_kernel<<<(int)(((long)G * AREAL * 77 + 255) / 256), 256, 0, stream>>>(
        linpart, anchors, cls_b, reg_b, out + (long)b0 * AREAL * 77, G);
  }
}